// Round 10
// baseline (290.572 us; speedup 1.0000x reference)
//
#include <hip/hip_runtime.h>

// MQA forward on MI355X (gfx950), bf16 MFMA path.
// B=2, S=2048, D_MODEL=2048, H=16, HEAD_DIM=128 (MQA: K/V shared across heads).
// R2: T2 XOR-swizzle in flash (bank conflicts 9.1e7 -> 0; 290 -> 191 us).
// R4: 2-phase dbuf staging (vmcnt(8)): -2%. Kept.
// R5: direct-global K/V frags: -87% (uncoalesced gather). REVERTED.
// R6: softmax-lite (deferred l-sum, T13 defer-max): 187 -> 167 us.
// R7: swapped-operand flash (lane owns one q-row): 167 -> 139 us.
// R8: cvt_pk inline asm: REVERTED (m240). exp2-direct kept.
// R9: 2 heads per block: 139 -> 132.6 us.
// R10: K/V fragment SHARING across the 2 heads (MQA): each ds_read_b128 feeds
//      both heads' MFMAs -> LDS b128 traffic halved (kernel is LDS-BW-bound);
//      lP holds both heads (LDS 80KB, still 2 blocks/CU).

typedef __attribute__((ext_vector_type(8))) short short8;
typedef __attribute__((ext_vector_type(4))) float f32x4;
typedef __attribute__((ext_vector_type(4))) unsigned int uint4v;

__device__ __forceinline__ unsigned short f2bf(float f) {
  unsigned int u = __float_as_uint(f);
  u += 0x7FFF + ((u >> 16) & 1);   // RNE
  return (unsigned short)(u >> 16);
}

__device__ __forceinline__ unsigned int pk2(float a, float b) {
  return (unsigned int)f2bf(a) | ((unsigned int)f2bf(b) << 16);
}

// async global->LDS 16B: dst must be wave-uniform (HW adds lane*16)
__device__ __forceinline__ void gll16(const void* g, void* lds) {
  __builtin_amdgcn_global_load_lds(
      (const __attribute__((address_space(1))) unsigned int*)g,
      (__attribute__((address_space(3))) unsigned int*)lds, 16, 0, 0);
}

// ---------------- elementwise f32 -> bf16 ----------------
__global__ __launch_bounds__(256) void cvtk(const float* __restrict__ in,
                                            unsigned short* __restrict__ out, int n4) {
  int i = blockIdx.x * blockDim.x + threadIdx.x;
  int stride = gridDim.x * blockDim.x;
  for (; i < n4; i += stride) {
    float4 v = reinterpret_cast<const float4*>(in)[i];
    ushort4 o;
    o.x = f2bf(v.x); o.y = f2bf(v.y); o.z = f2bf(v.z); o.w = f2bf(v.w);
    reinterpret_cast<ushort4*>(out)[i] = o;
  }
}

// ------- transpose + convert (paired): W[K][N] f32 -> Wt[N][K] bf16, z selects -------
__global__ __launch_bounds__(256) void tcvt2(const float* __restrict__ W0, const float* __restrict__ W1,
                                             unsigned short* __restrict__ D0, unsigned short* __restrict__ D1,
                                             int K, int N) {
  const float* W = blockIdx.z ? W1 : W0;
  unsigned short* Wt = blockIdx.z ? D1 : D0;
  __shared__ float tile[32][33];
  int n0 = blockIdx.x * 32, k0 = blockIdx.y * 32;
  int tx = threadIdx.x, ty = threadIdx.y;
  #pragma unroll
  for (int i = 0; i < 32; i += 8)
    tile[ty + i][tx] = W[(size_t)(k0 + ty + i) * N + n0 + tx];
  __syncthreads();
  #pragma unroll
  for (int i = 0; i < 32; i += 8)
    Wt[(size_t)(n0 + ty + i) * K + k0 + tx] = f2bf(tile[tx][ty + i]);
}

// ---------------- GEMM: C = A[M][K] @ Bt[N][K]^T + bias ----------------
// 128x128 tile, BK=64, 256 threads = 4 waves (2x2 of 64x64), m97-style.
// MODE 1: f32 out C[M][N] (+b0)
// MODE 3: fused QKV epilogue (N=2304):
//   col<2048   -> qb[row][col] bf16 = (acc+b0)*cmul
//   col<2176   -> kbuf[row][col-2048] bf16 (+b1)
//   else       -> vt[b][col-2176][s] bf16 (+b2), transposed
template <int MODE>
__global__ __launch_bounds__(256)
void gemm_nt(const unsigned short* __restrict__ A, const unsigned short* __restrict__ Bt,
             const float* __restrict__ b0, const float* __restrict__ b1,
             const float* __restrict__ b2,
             void* __restrict__ C, unsigned short* __restrict__ C2,
             unsigned short* __restrict__ C3, int M, int N, int K, float cmul) {
  __shared__ unsigned short lA[128 * 64];
  __shared__ unsigned short lB[128 * 64];
  const int t = threadIdx.x;
  const int lane = t & 63;
  const int w = t >> 6;
  const int wr = w >> 1, wc = w & 1;
  const int r15 = lane & 15, g4 = lane >> 4;
  const int tileM = blockIdx.y * 128;
  const int tileN = blockIdx.x * 128;

  f32x4 acc[4][4];
  #pragma unroll
  for (int i = 0; i < 4; i++)
    #pragma unroll
    for (int j = 0; j < 4; j++) acc[i][j] = (f32x4){0.f, 0.f, 0.f, 0.f};

  const int nkt = K >> 6;
  for (int kt = 0; kt < nkt; ++kt) {
    const int k0 = kt * 64;
    #pragma unroll
    for (int i = 0; i < 4; ++i) {
      int flat = i * 256 + t;
      int row = flat >> 3, gc = flat & 7;            // [128 rows][8 granules of 8 bf16]
      unsigned lb = (unsigned)(i * 256 + w * 64) * 16; // wave-uniform LDS byte base
      gll16(A  + (size_t)(tileM + row) * K + k0 + gc * 8, (char*)lA + lb);
      gll16(Bt + (size_t)(tileN + row) * K + k0 + gc * 8, (char*)lB + lb);
    }
    __syncthreads();
    #pragma unroll
    for (int kk = 0; kk < 2; ++kk) {
      short8 af[4], bf[4];
      #pragma unroll
      for (int mt = 0; mt < 4; ++mt)
        af[mt] = *reinterpret_cast<const short8*>(&lA[(wr * 64 + mt * 16 + r15) * 64 + kk * 32 + g4 * 8]);
      #pragma unroll
      for (int nt = 0; nt < 4; ++nt)
        bf[nt] = *reinterpret_cast<const short8*>(&lB[(wc * 64 + nt * 16 + r15) * 64 + kk * 32 + g4 * 8]);
      #pragma unroll
      for (int mt = 0; mt < 4; ++mt)
        #pragma unroll
        for (int nt = 0; nt < 4; ++nt)
          acc[mt][nt] = __builtin_amdgcn_mfma_f32_16x16x32_bf16(af[mt], bf[nt], acc[mt][nt], 0, 0, 0);
    }
    __syncthreads();
  }

  // epilogue: C/D layout col=lane&15, row=(lane>>4)*4+reg
  #pragma unroll
  for (int mt = 0; mt < 4; ++mt) {
    #pragma unroll
    for (int nt = 0; nt < 4; ++nt) {
      int col = tileN + wc * 64 + nt * 16 + r15;
      #pragma unroll
      for (int r = 0; r < 4; ++r) {
        int row = tileM + wr * 64 + mt * 16 + g4 * 4 + r;
        float v = acc[mt][nt][r];
        if (MODE == 1) {
          ((float*)C)[(size_t)row * N + col] = v + b0[col];
        } else {
          if (col < 2048) {
            ((unsigned short*)C)[(size_t)row * 2048 + col] = f2bf((v + b0[col]) * cmul);
          } else if (col < 2176) {
            int dd = col - 2048;
            C2[(size_t)row * 128 + dd] = f2bf(v + b1[dd]);
          } else {
            int dd = col - 2176;
            int bb = row >> 11, s = row & 2047;
            C3[((size_t)bb * 128 + dd) * 2048 + s] = f2bf(v + b2[dd]);  // v^T [b][d][s]
          }
        }
      }
    }
  }
}

// ---------------- flash attention (MQA), swapped ops, 2 heads, shared frags ----------------
// grid (S/64, H/2, B), 256 threads = 4 waves; wave owns 16 q rows (q = r15 per lane).
// qb [B*S][2048] bf16 (pre-scaled by log2(e)/sqrt(d)), kb [B*S][128] bf16,
// vt [B][128][S] bf16, ob [B*S][2048] bf16
// QK^T = mfma(K,Q): D[kv][q]; PV = mfma(V^T,P^T): D[d][q]; softmax lane-local.
// Each K/V b128 fragment read ONCE, feeds both heads (MQA shares K/V) ->
// halves LDS traffic (the bottleneck). lP[wave][head][q][kv], granule ^r15.
__global__ __launch_bounds__(256)
void flash_mqa(const unsigned short* __restrict__ qb, const unsigned short* __restrict__ kb,
               const unsigned short* __restrict__ vt, unsigned short* __restrict__ ob) {
  __shared__ unsigned short lK[2][64 * 128];     // [kv][d], swizzled
  __shared__ unsigned short lV[2][128 * 64];     // [d][kv], swizzled
  __shared__ unsigned short lP[4][2][16 * 64];   // per-wave, per-head [q][kv]

  const int t = threadIdx.x;
  const int lane = t & 63;
  const int w = t >> 6;
  const int r15 = lane & 15, g4 = lane >> 4;
  const int qt = blockIdx.x, hy = blockIdx.y, b = blockIdx.z;
  const int q0 = qt * 64 + w * 16;

  // persistent Q B-frags for 2 heads: row q=r15, k = g4*8
  short8 qf0[4], qf1[4];
  const size_t qrow = (size_t)(b * 2048 + q0 + r15);
  #pragma unroll
  for (int kk = 0; kk < 4; ++kk) {
    qf0[kk] = *reinterpret_cast<const short8*>(
        &qb[qrow * 2048 + (hy * 2 + 0) * 128 + kk * 32 + g4 * 8]);
    qf1[kk] = *reinterpret_cast<const short8*>(
        &qb[qrow * 2048 + (hy * 2 + 1) * 128 + kk * 32 + g4 * 8]);
  }

  f32x4 oacc0[8], oacc1[8];   // O^T: [ot][r] -> d = ot*16+g4*4+r, q = r15
  #pragma unroll
  for (int i = 0; i < 8; i++) {
    oacc0[i] = (f32x4){0.f, 0.f, 0.f, 0.f};
    oacc1[i] = (f32x4){0.f, 0.f, 0.f, 0.f};
  }
  float m0 = -1e30f, m1 = -1e30f, l0 = 0.f, l1 = 0.f;  // log2 units

  const unsigned short* kbase = kb + (size_t)b * 2048 * 128;
  const unsigned short* vbase = vt + (size_t)b * 128 * 2048;

  auto stage = [&](int buf, int kv0) {
    #pragma unroll
    for (int i = 0; i < 4; ++i) {
      int flat = i * 256 + t;
      unsigned lb = (unsigned)(i * 256 + w * 64) * 16;
      { int row = flat >> 4, gc = flat & 15;
        gll16(kbase + (size_t)(kv0 + row) * 128 + ((gc ^ (row & 15)) << 3), (char*)lK[buf] + lb); }
      { int row = flat >> 3, gc = flat & 7;
        gll16(vbase + (size_t)row * 2048 + kv0 + ((gc ^ (row & 7)) << 3), (char*)lV[buf] + lb); }
    }
  };

  stage(0, 0);
  int cur = 0;
  for (int it = 0; it < 32; ++it) {
    if (it < 31) {
      stage(cur ^ 1, (it + 1) * 64);
      asm volatile("s_waitcnt vmcnt(8)" ::: "memory");  // current tile's 8 loads done
    } else {
      asm volatile("s_waitcnt vmcnt(0)" ::: "memory");
    }
    __builtin_amdgcn_s_barrier();
    asm volatile("" ::: "memory");

    const unsigned short* cK = lK[cur];
    const unsigned short* cV = lV[cur];

    // ---- QK^T both heads, kf read ONCE: D[kv][q] (log2-scaled) ----
    f32x4 s0[4], s1[4];
    #pragma unroll
    for (int ct = 0; ct < 4; ct++) {
      s0[ct] = (f32x4){0.f, 0.f, 0.f, 0.f};
      s1[ct] = (f32x4){0.f, 0.f, 0.f, 0.f};
    }
    #pragma unroll
    for (int kk = 0; kk < 4; ++kk) {
      #pragma unroll
      for (int ct = 0; ct < 4; ++ct) {
        const int krow = ct * 16 + r15;
        const int kg = (kk * 4 + g4) ^ (krow & 15);
        short8 kf = *reinterpret_cast<const short8*>(&cK[krow * 128 + kg * 8]);
        s0[ct] = __builtin_amdgcn_mfma_f32_16x16x32_bf16(kf, qf0[kk], s0[ct], 0, 0, 0);
        s1[ct] = __builtin_amdgcn_mfma_f32_16x16x32_bf16(kf, qf1[kk], s1[ct], 0, 0, 0);
      }
    }

    // ---- softmax per head (lane owns q=r15, 16 kv values) ----
    {
      float mx = s0[0][0];
      #pragma unroll
      for (int ct = 0; ct < 4; ++ct)
        #pragma unroll
        for (int r = 0; r < 4; ++r) mx = fmaxf(mx, s0[ct][r]);
      mx = fmaxf(mx, __shfl_xor(mx, 16));
      mx = fmaxf(mx, __shfl_xor(mx, 32));
      if (__any(mx > m0 + 11.5416f)) {
        float mn = fmaxf(m0, mx);
        float rf = exp2f(m0 - mn);
        m0 = mn; l0 *= rf;
        #pragma unroll
        for (int ot = 0; ot < 8; ++ot)
          #pragma unroll
          for (int r = 0; r < 4; ++r) oacc0[ot][r] *= rf;
      }
      #pragma unroll
      for (int ct = 0; ct < 4; ++ct) {
        float p0 = exp2f(s0[ct][0] - m0);
        float p1 = exp2f(s0[ct][1] - m0);
        float p2 = exp2f(s0[ct][2] - m0);
        float p3 = exp2f(s0[ct][3] - m0);
        l0 += (p0 + p1) + (p2 + p3);
        const int gi = (ct * 4 + g4) ^ r15;
        *reinterpret_cast<uint2*>(&lP[w][0][r15 * 64 + gi * 4]) = make_uint2(pk2(p0, p1), pk2(p2, p3));
      }
    }
    {
      float mx = s1[0][0];
      #pragma unroll
      for (int ct = 0; ct < 4; ++ct)
        #pragma unroll
        for (int r = 0; r < 4; ++r) mx = fmaxf(mx, s1[ct][r]);
      mx = fmaxf(mx, __shfl_xor(mx, 16));
      mx = fmaxf(mx, __shfl_xor(mx, 32));
      if (__any(mx > m1 + 11.5416f)) {
        float mn = fmaxf(m1, mx);
        float rf = exp2f(m1 - mn);
        m1 = mn; l1 *= rf;
        #pragma unroll
        for (int ot = 0; ot < 8; ++ot)
          #pragma unroll
          for (int r = 0; r < 4; ++r) oacc1[ot][r] *= rf;
      }
      #pragma unroll
      for (int ct = 0; ct < 4; ++ct) {
        float p0 = exp2f(s1[ct][0] - m1);
        float p1 = exp2f(s1[ct][1] - m1);
        float p2 = exp2f(s1[ct][2] - m1);
        float p3 = exp2f(s1[ct][3] - m1);
        l1 += (p0 + p1) + (p2 + p3);
        const int gi = (ct * 4 + g4) ^ r15;
        *reinterpret_cast<uint2*>(&lP[w][1][r15 * 64 + gi * 4]) = make_uint2(pk2(p0, p1), pk2(p2, p3));
      }
    }

    // ---- PV both heads, vf read ONCE: oacc = V^T_sub(ot) x P^T -> D[d][q] ----
    #pragma unroll
    for (int kk = 0; kk < 2; ++kk) {
      const int gA = (kk * 8 + g4 * 2) ^ r15;
      const int gB = (kk * 8 + g4 * 2 + 1) ^ r15;
      const uint2 wa0 = *reinterpret_cast<const uint2*>(&lP[w][0][r15 * 64 + gA * 4]);
      const uint2 wb0 = *reinterpret_cast<const uint2*>(&lP[w][0][r15 * 64 + gB * 4]);
      const uint2 wa1 = *reinterpret_cast<const uint2*>(&lP[w][1][r15 * 64 + gA * 4]);
      const uint2 wb1 = *reinterpret_cast<const uint2*>(&lP[w][1][r15 * 64 + gB * 4]);
      uint4v pw0 = {wa0.x, wa0.y, wb0.x, wb0.y};
      uint4v pw1 = {wa1.x, wa1.y, wb1.x, wb1.y};
      short8 pf0 = __builtin_bit_cast(short8, pw0);
      short8 pf1 = __builtin_bit_cast(short8, pw1);
      #pragma unroll
      for (int ot = 0; ot < 8; ++ot) {
        const int vrow = ot * 16 + r15;
        const int vg = (kk * 4 + g4) ^ (vrow & 7);
        short8 vf = *reinterpret_cast<const short8*>(&cV[vrow * 64 + vg * 8]);
        oacc0[ot] = __builtin_amdgcn_mfma_f32_16x16x32_bf16(vf, pf0, oacc0[ot], 0, 0, 0);
        oacc1[ot] = __builtin_amdgcn_mfma_f32_16x16x32_bf16(vf, pf1, oacc1[ot], 0, 0, 0);
      }
    }

    asm volatile("" ::: "memory");
    __builtin_amdgcn_s_barrier();   // all waves done reading buf[cur] before restage
    cur ^= 1;
  }

  // epilogue: cross-lane l reduce (kv partials live on lanes r15, r15+16, +32, +48)
  const int row = q0 + r15;
  {
    float l = l0;
    l += __shfl_xor(l, 16);
    l += __shfl_xor(l, 32);
    const float inv = 1.0f / l;
    const size_t base = ((size_t)(b * 2048 + row)) * 2048 + (hy * 2 + 0) * 128;
    #pragma unroll
    for (int ot = 0; ot < 8; ++ot) {
      uint2 pw = make_uint2(pk2(oacc0[ot][0] * inv, oacc0[ot][1] * inv),
                            pk2(oacc0[ot][2] * inv, oacc0[ot][3] * inv));
      *reinterpret_cast<uint2*>(&ob[base + ot * 16 + g4 * 4]) = pw;
    }
  }
  {
    float l = l1;
    l += __shfl_xor(l, 16);
    l += __shfl_xor(l, 32);
    const float inv = 1.0f / l;
    const size_t base = ((size_t)(b * 2048 + row)) * 2048 + (hy * 2 + 1) * 128;
    #pragma unroll
    for (int ot = 0; ot < 8; ++ot) {
      uint2 pw = make_uint2(pk2(oacc1[ot][0] * inv, oacc1[ot][1] * inv),
                            pk2(oacc1[ot][2] * inv, oacc1[ot][3] * inv));
      *reinterpret_cast<uint2*>(&ob[base + ot * 16 + g4 * 4]) = pw;
    }
  }
}

extern "C" void kernel_launch(void* const* d_in, const int* in_sizes, int n_in,
                              void* d_out, int out_size, void* d_ws, size_t ws_size,
                              hipStream_t stream) {
  const float* x  = (const float*)d_in[0];
  const float* Wq = (const float*)d_in[1];
  const float* bq = (const float*)d_in[2];
  const float* Wk = (const float*)d_in[3];
  const float* bk = (const float*)d_in[4];
  const float* Wv = (const float*)d_in[5];
  const float* bv = (const float*)d_in[6];
  const float* Wo = (const float*)d_in[7];
  const float* bo = (const float*)d_in[8];
  float* out = (float*)d_out;

  char* ws = (char*)d_ws;
  size_t off = 0;
  auto alloc = [&](size_t elems) {
    unsigned short* p = (unsigned short*)(ws + off);
    off += (elems * 2 + 255) & ~(size_t)255;
    return p;
  };
  unsigned short* xb    = alloc(8388608);   // x bf16 [4096][2048]
  unsigned short* qb    = alloc(8388608);   // q bf16 [4096][2048] (pre-scaled, log2 units)
  unsigned short* ob    = alloc(8388608);   // attn out bf16 [4096][2048]
  unsigned short* wqkvt = alloc(4718592);   // [Wq^T;Wk^T;Wv^T] [2304][2048]
  unsigned short* wot   = alloc(4194304);   // Wo^T [2048][2048]
  unsigned short* kbuf  = alloc(524288);    // k bf16 [4096][128]
  unsigned short* vtb   = alloc(524288);    // v^T bf16 [2][128][2048]

  // 1/sqrt(128) * log2(e): scores come out of QK^T already in log2 units
  const float qscale = 0.08838834764831845f * 1.44269504088896f;

  dim3 tb(32, 8);
  cvtk<<<4096, 256, 0, stream>>>(x, xb, 2097152);
  tcvt2<<<dim3(64, 64, 2), tb, 0, stream>>>(Wq, Wo, wqkvt, wot, 2048, 2048);
  tcvt2<<<dim3(4, 64, 2),  tb, 0, stream>>>(Wk, Wv, wqkvt + (size_t)2048 * 2048,
                                            wqkvt + (size_t)2176 * 2048, 2048, 128);

  gemm_nt<3><<<dim3(18, 32), 256, 0, stream>>>(xb, wqkvt, bq, bk, bv,
                                               qb, kbuf, vtb, 4096, 2304, 2048, qscale);
  flash_mqa<<<dim3(32, 8, 2), 256, 0, stream>>>(qb, kbuf, vtb, ob);
  gemm_nt<1><<<dim3(16, 32), 256, 0, stream>>>(ob, wot, bo, nullptr, nullptr,
                                               out, nullptr, nullptr, 4096, 2048, 2048, 1.0f);
}

// Round 11
// 287.635 us; speedup vs baseline: 1.0102x; 1.0102x over previous
//
#include <hip/hip_runtime.h>

// MQA forward on MI355X (gfx950), bf16 MFMA path.
// B=2, S=2048, D_MODEL=2048, H=16, HEAD_DIM=128 (MQA: K/V shared across heads).
// R2: T2 XOR-swizzle in flash (bank conflicts 9.1e7 -> 0; 290 -> 191 us).
// R4: 2-phase dbuf staging in flash (vmcnt(8)): -2%. Kept.
// R5: direct-global K/V frags: -87% (uncoalesced gather). REVERTED.
// R6: softmax-lite (deferred l-sum, T13 defer-max): 187 -> 167 us.
// R7: swapped-operand flash (lane owns one q-row): 167 -> 139 us.
// R8: cvt_pk inline asm: REVERTED (m240). exp2-direct kept.
// R9: 2 heads per block: 139 -> 132.6 us.
// R10: K/V frag sharing across heads: -3% (VALU up, LDS-BW was NOT the limit). REVERTED.
// R11: GEMM 2-phase dbuf (stage-next-first, drain-at-end, 1 barrier/tile) --
//      hides stage latency under MFMA; targets the ~132us GEMM half.

typedef __attribute__((ext_vector_type(8))) short short8;
typedef __attribute__((ext_vector_type(4))) float f32x4;
typedef __attribute__((ext_vector_type(4))) unsigned int uint4v;

__device__ __forceinline__ unsigned short f2bf(float f) {
  unsigned int u = __float_as_uint(f);
  u += 0x7FFF + ((u >> 16) & 1);   // RNE
  return (unsigned short)(u >> 16);
}

__device__ __forceinline__ unsigned int pk2(float a, float b) {
  return (unsigned int)f2bf(a) | ((unsigned int)f2bf(b) << 16);
}

// async global->LDS 16B: dst must be wave-uniform (HW adds lane*16)
__device__ __forceinline__ void gll16(const void* g, void* lds) {
  __builtin_amdgcn_global_load_lds(
      (const __attribute__((address_space(1))) unsigned int*)g,
      (__attribute__((address_space(3))) unsigned int*)lds, 16, 0, 0);
}

// ---------------- elementwise f32 -> bf16 ----------------
__global__ __launch_bounds__(256) void cvtk(const float* __restrict__ in,
                                            unsigned short* __restrict__ out, int n4) {
  int i = blockIdx.x * blockDim.x + threadIdx.x;
  int stride = gridDim.x * blockDim.x;
  for (; i < n4; i += stride) {
    float4 v = reinterpret_cast<const float4*>(in)[i];
    ushort4 o;
    o.x = f2bf(v.x); o.y = f2bf(v.y); o.z = f2bf(v.z); o.w = f2bf(v.w);
    reinterpret_cast<ushort4*>(out)[i] = o;
  }
}

// ------- transpose + convert (paired): W[K][N] f32 -> Wt[N][K] bf16, z selects -------
__global__ __launch_bounds__(256) void tcvt2(const float* __restrict__ W0, const float* __restrict__ W1,
                                             unsigned short* __restrict__ D0, unsigned short* __restrict__ D1,
                                             int K, int N) {
  const float* W = blockIdx.z ? W1 : W0;
  unsigned short* Wt = blockIdx.z ? D1 : D0;
  __shared__ float tile[32][33];
  int n0 = blockIdx.x * 32, k0 = blockIdx.y * 32;
  int tx = threadIdx.x, ty = threadIdx.y;
  #pragma unroll
  for (int i = 0; i < 32; i += 8)
    tile[ty + i][tx] = W[(size_t)(k0 + ty + i) * N + n0 + tx];
  __syncthreads();
  #pragma unroll
  for (int i = 0; i < 32; i += 8)
    Wt[(size_t)(n0 + ty + i) * K + k0 + tx] = f2bf(tile[tx][ty + i]);
}

// ---------------- GEMM: C = A[M][K] @ Bt[N][K]^T + bias, 2-phase dbuf ----------------
// 128x128 tile, BK=64, 256 threads = 4 waves (2x2 of 64x64).
// Per K-tile: stage(next tile -> other buffer) issued FIRST; ds_read+MFMA on
// current buffer; then vmcnt(0) (drain next-tile writes, latency already hidden
// under the 32-MFMA compute) + ONE s_barrier. LDS 64KB -> 2 blocks/CU.
// MODE 1: f32 out C[M][N] (+b0)
// MODE 3: fused QKV epilogue (N=2304): col<2048 -> qb bf16 (acc+b0)*cmul;
//         col<2176 -> kbuf bf16 (+b1); else -> vt transposed bf16 (+b2)
template <int MODE>
__global__ __launch_bounds__(256)
void gemm_nt(const unsigned short* __restrict__ A, const unsigned short* __restrict__ Bt,
             const float* __restrict__ b0, const float* __restrict__ b1,
             const float* __restrict__ b2,
             void* __restrict__ C, unsigned short* __restrict__ C2,
             unsigned short* __restrict__ C3, int M, int N, int K, float cmul) {
  __shared__ unsigned short lA[2][128 * 64];
  __shared__ unsigned short lB[2][128 * 64];
  const int t = threadIdx.x;
  const int lane = t & 63;
  const int w = t >> 6;
  const int wr = w >> 1, wc = w & 1;
  const int r15 = lane & 15, g4 = lane >> 4;
  const int tileM = blockIdx.y * 128;
  const int tileN = blockIdx.x * 128;

  f32x4 acc[4][4];
  #pragma unroll
  for (int i = 0; i < 4; i++)
    #pragma unroll
    for (int j = 0; j < 4; j++) acc[i][j] = (f32x4){0.f, 0.f, 0.f, 0.f};

  auto stage = [&](int buf, int kt) {
    const int k0 = kt * 64;
    #pragma unroll
    for (int i = 0; i < 4; ++i) {
      int flat = i * 256 + t;
      int row = flat >> 3, gc = flat & 7;            // [128 rows][8 granules of 8 bf16]
      unsigned lb = (unsigned)(i * 256 + w * 64) * 16; // wave-uniform LDS byte base
      gll16(A  + (size_t)(tileM + row) * K + k0 + gc * 8, (char*)lA[buf] + lb);
      gll16(Bt + (size_t)(tileN + row) * K + k0 + gc * 8, (char*)lB[buf] + lb);
    }
  };

  const int nkt = K >> 6;
  stage(0, 0);
  asm volatile("s_waitcnt vmcnt(0)" ::: "memory");
  __builtin_amdgcn_s_barrier();
  asm volatile("" ::: "memory");

  int cur = 0;
  for (int kt = 0; kt < nkt; ++kt) {
    if (kt + 1 < nkt) stage(cur ^ 1, kt + 1);   // issue early: latency hides under MFMA

    const unsigned short* cA = lA[cur];
    const unsigned short* cB = lB[cur];
    #pragma unroll
    for (int kk = 0; kk < 2; ++kk) {
      short8 af[4], bf[4];
      #pragma unroll
      for (int mt = 0; mt < 4; ++mt)
        af[mt] = *reinterpret_cast<const short8*>(&cA[(wr * 64 + mt * 16 + r15) * 64 + kk * 32 + g4 * 8]);
      #pragma unroll
      for (int nt = 0; nt < 4; ++nt)
        bf[nt] = *reinterpret_cast<const short8*>(&cB[(wc * 64 + nt * 16 + r15) * 64 + kk * 32 + g4 * 8]);
      #pragma unroll
      for (int mt = 0; mt < 4; ++mt)
        #pragma unroll
        for (int nt = 0; nt < 4; ++nt)
          acc[mt][nt] = __builtin_amdgcn_mfma_f32_16x16x32_bf16(af[mt], bf[nt], acc[mt][nt], 0, 0, 0);
    }

    if (kt + 1 < nkt) {
      asm volatile("s_waitcnt vmcnt(0)" ::: "memory");  // next tile's writes landed
      __builtin_amdgcn_s_barrier();                     // all waves done reading cur
      asm volatile("" ::: "memory");
    }
    cur ^= 1;
  }

  // epilogue: C/D layout col=lane&15, row=(lane>>4)*4+reg
  #pragma unroll
  for (int mt = 0; mt < 4; ++mt) {
    #pragma unroll
    for (int nt = 0; nt < 4; ++nt) {
      int col = tileN + wc * 64 + nt * 16 + r15;
      #pragma unroll
      for (int r = 0; r < 4; ++r) {
        int row = tileM + wr * 64 + mt * 16 + g4 * 4 + r;
        float v = acc[mt][nt][r];
        if (MODE == 1) {
          ((float*)C)[(size_t)row * N + col] = v + b0[col];
        } else {
          if (col < 2048) {
            ((unsigned short*)C)[(size_t)row * 2048 + col] = f2bf((v + b0[col]) * cmul);
          } else if (col < 2176) {
            int dd = col - 2048;
            C2[(size_t)row * 128 + dd] = f2bf(v + b1[dd]);
          } else {
            int dd = col - 2176;
            int bb = row >> 11, s = row & 2047;
            C3[((size_t)bb * 128 + dd) * 2048 + s] = f2bf(v + b2[dd]);  // v^T [b][d][s]
          }
        }
      }
    }
  }
}

// ---------------- flash attention (MQA), swapped operands, 2 heads/block (R9) ----------------
// grid (S/64, H/2, B), 256 threads = 4 waves; wave owns 16 q rows (q = r15 per lane).
// qb [B*S][2048] bf16 (pre-scaled by log2(e)/sqrt(d)), kb [B*S][128] bf16,
// vt [B][128][S] bf16, ob [B*S][2048] bf16
// QK^T = mfma(K,Q): D[kv][q]; softmax lane-local (q=r15); P=exp2(s'-m').
// PV  = mfma(V^T,P^T): D[d][q]; rescale lane-local.
// 2 heads share the staged K/V tile (MQA) -> stage/barrier cost amortized 2x.
__global__ __launch_bounds__(256)
void flash_mqa(const unsigned short* __restrict__ qb, const unsigned short* __restrict__ kb,
               const unsigned short* __restrict__ vt, unsigned short* __restrict__ ob) {
  __shared__ unsigned short lK[2][64 * 128];   // [kv][d], swizzled
  __shared__ unsigned short lV[2][128 * 64];   // [d][kv], swizzled
  __shared__ unsigned short lP[4][16 * 64];    // per-wave [q][kv], granule-swizzled

  const int t = threadIdx.x;
  const int lane = t & 63;
  const int w = t >> 6;
  const int r15 = lane & 15, g4 = lane >> 4;
  const int qt = blockIdx.x, hy = blockIdx.y, b = blockIdx.z;
  const int q0 = qt * 64 + w * 16;

  // persistent Q B-frags for 2 heads: row q=r15, k = g4*8
  short8 qf[2][4];
  const size_t qrow = (size_t)(b * 2048 + q0 + r15);
  #pragma unroll
  for (int hh = 0; hh < 2; ++hh)
    #pragma unroll
    for (int kk = 0; kk < 4; ++kk)
      qf[hh][kk] = *reinterpret_cast<const short8*>(
          &qb[qrow * 2048 + (hy * 2 + hh) * 128 + kk * 32 + g4 * 8]);

  f32x4 oacc[2][8];   // O^T: oacc[hh][ot][r] -> d = ot*16+g4*4+r, q = r15
  #pragma unroll
  for (int hh = 0; hh < 2; ++hh)
    #pragma unroll
    for (int i = 0; i < 8; i++) oacc[hh][i] = (f32x4){0.f, 0.f, 0.f, 0.f};
  float m_q[2] = {-1e30f, -1e30f}, l_q[2] = {0.f, 0.f};  // log2 units

  const unsigned short* kbase = kb + (size_t)b * 2048 * 128;
  const unsigned short* vbase = vt + (size_t)b * 128 * 2048;

  auto stage = [&](int buf, int kv0) {
    #pragma unroll
    for (int i = 0; i < 4; ++i) {
      int flat = i * 256 + t;
      unsigned lb = (unsigned)(i * 256 + w * 64) * 16;
      { int row = flat >> 4, gc = flat & 15;
        gll16(kbase + (size_t)(kv0 + row) * 128 + ((gc ^ (row & 15)) << 3), (char*)lK[buf] + lb); }
      { int row = flat >> 3, gc = flat & 7;
        gll16(vbase + (size_t)row * 2048 + kv0 + ((gc ^ (row & 7)) << 3), (char*)lV[buf] + lb); }
    }
  };

  stage(0, 0);
  int cur = 0;
  for (int it = 0; it < 32; ++it) {
    if (it < 31) {
      stage(cur ^ 1, (it + 1) * 64);
      asm volatile("s_waitcnt vmcnt(8)" ::: "memory");  // current tile's 8 loads done
    } else {
      asm volatile("s_waitcnt vmcnt(0)" ::: "memory");
    }
    __builtin_amdgcn_s_barrier();
    asm volatile("" ::: "memory");

    const unsigned short* cK = lK[cur];
    const unsigned short* cV = lV[cur];

    #pragma unroll
    for (int hh = 0; hh < 2; ++hh) {
      // ---- QK^T swapped: s[ct] = K_sub(ct) x Q -> D[kv][q] (log2-scaled) ----
      f32x4 s[4];
      #pragma unroll
      for (int ct = 0; ct < 4; ct++) s[ct] = (f32x4){0.f, 0.f, 0.f, 0.f};
      #pragma unroll
      for (int kk = 0; kk < 4; ++kk) {
        #pragma unroll
        for (int ct = 0; ct < 4; ++ct) {
          const int krow = ct * 16 + r15;
          const int kg = (kk * 4 + g4) ^ (krow & 15);
          short8 kf = *reinterpret_cast<const short8*>(&cK[krow * 128 + kg * 8]);
          s[ct] = __builtin_amdgcn_mfma_f32_16x16x32_bf16(kf, qf[hh][kk], s[ct], 0, 0, 0);
        }
      }

      // ---- softmax: lane owns q=r15 with 16 kv values ----
      float mx = s[0][0];
      #pragma unroll
      for (int ct = 0; ct < 4; ++ct)
        #pragma unroll
        for (int r = 0; r < 4; ++r) mx = fmaxf(mx, s[ct][r]);
      mx = fmaxf(mx, __shfl_xor(mx, 16));
      mx = fmaxf(mx, __shfl_xor(mx, 32));
      // T13 defer-max: rescale only when growth > 8/ln2 (P bounded by e^8)
      if (__any(mx > m_q[hh] + 11.5416f)) {
        float mn = fmaxf(m_q[hh], mx);
        float rf = exp2f(m_q[hh] - mn);   // lane-local (q=r15)
        m_q[hh] = mn;
        l_q[hh] *= rf;
        #pragma unroll
        for (int ot = 0; ot < 8; ++ot)
          #pragma unroll
          for (int r = 0; r < 4; ++r) oacc[hh][ot][r] *= rf;
      }
      // ---- P = exp2(s-m), pack, b64 write to lP (granule ^ r15) ----
      #pragma unroll
      for (int ct = 0; ct < 4; ++ct) {
        float p0 = exp2f(s[ct][0] - m_q[hh]);
        float p1 = exp2f(s[ct][1] - m_q[hh]);
        float p2 = exp2f(s[ct][2] - m_q[hh]);
        float p3 = exp2f(s[ct][3] - m_q[hh]);
        l_q[hh] += (p0 + p1) + (p2 + p3);
        const int gi = (ct * 4 + g4) ^ r15;
        *reinterpret_cast<uint2*>(&lP[w][r15 * 64 + gi * 4]) = make_uint2(pk2(p0, p1), pk2(p2, p3));
      }

      // ---- PV swapped: oacc = V^T_sub(ot) x P^T -> D[d][q] ----
      #pragma unroll
      for (int kk = 0; kk < 2; ++kk) {
        const int gA = (kk * 8 + g4 * 2) ^ r15;
        const int gB = (kk * 8 + g4 * 2 + 1) ^ r15;
        const uint2 wa = *reinterpret_cast<const uint2*>(&lP[w][r15 * 64 + gA * 4]);
        const uint2 wb = *reinterpret_cast<const uint2*>(&lP[w][r15 * 64 + gB * 4]);
        uint4v pw = {wa.x, wa.y, wb.x, wb.y};
        short8 pf = __builtin_bit_cast(short8, pw);
        #pragma unroll
        for (int ot = 0; ot < 8; ++ot) {
          const int vrow = ot * 16 + r15;
          const int vg = (kk * 4 + g4) ^ (vrow & 7);
          short8 vf = *reinterpret_cast<const short8*>(&cV[vrow * 64 + vg * 8]);
          oacc[hh][ot] = __builtin_amdgcn_mfma_f32_16x16x32_bf16(vf, pf, oacc[hh][ot], 0, 0, 0);
        }
      }
    }

    asm volatile("" ::: "memory");
    __builtin_amdgcn_s_barrier();   // all waves done reading buf[cur] before restage
    cur ^= 1;
  }

  // epilogue: cross-lane l reduce (kv partials live on lanes r15, r15+16, +32, +48)
  #pragma unroll
  for (int hh = 0; hh < 2; ++hh) {
    float l = l_q[hh];
    l += __shfl_xor(l, 16);
    l += __shfl_xor(l, 32);
    const float inv = 1.0f / l;
    const int row = q0 + r15;
    const size_t base = ((size_t)(b * 2048 + row)) * 2048 + (hy * 2 + hh) * 128;
    #pragma unroll
    for (int ot = 0; ot < 8; ++ot) {
      uint2 pw = make_uint2(pk2(oacc[hh][ot][0] * inv, oacc[hh][ot][1] * inv),
                            pk2(oacc[hh][ot][2] * inv, oacc[hh][ot][3] * inv));
      *reinterpret_cast<uint2*>(&ob[base + ot * 16 + g4 * 4]) = pw;
    }
  }
}

extern "C" void kernel_launch(void* const* d_in, const int* in_sizes, int n_in,
                              void* d_out, int out_size, void* d_ws, size_t ws_size,
                              hipStream_t stream) {
  const float* x  = (const float*)d_in[0];
  const float* Wq = (const float*)d_in[1];
  const float* bq = (const float*)d_in[2];
  const float* Wk = (const float*)d_in[3];
  const float* bk = (const float*)d_in[4];
  const float* Wv = (const float*)d_in[5];
  const float* bv = (const float*)d_in[6];
  const float* Wo = (const float*)d_in[7];
  const float* bo = (const float*)d_in[8];
  float* out = (float*)d_out;

  char* ws = (char*)d_ws;
  size_t off = 0;
  auto alloc = [&](size_t elems) {
    unsigned short* p = (unsigned short*)(ws + off);
    off += (elems * 2 + 255) & ~(size_t)255;
    return p;
  };
  unsigned short* xb    = alloc(8388608);   // x bf16 [4096][2048]
  unsigned short* qb    = alloc(8388608);   // q bf16 [4096][2048] (pre-scaled, log2 units)
  unsigned short* ob    = alloc(8388608);   // attn out bf16 [4096][2048]
  unsigned short* wqkvt = alloc(4718592);   // [Wq^T;Wk^T;Wv^T] [2304][2048]
  unsigned short* wot   = alloc(4194304);   // Wo^T [2048][2048]
  unsigned short* kbuf  = alloc(524288);    // k bf16 [4096][128]
  unsigned short* vtb   = alloc(524288);    // v^T bf16 [2][128][2048]

  // 1/sqrt(128) * log2(e): scores come out of QK^T already in log2 units
  const float qscale = 0.08838834764831845f * 1.44269504088896f;

  dim3 tb(32, 8);
  cvtk<<<4096, 256, 0, stream>>>(x, xb, 2097152);
  tcvt2<<<dim3(64, 64, 2), tb, 0, stream>>>(Wq, Wo, wqkvt, wot, 2048, 2048);
  tcvt2<<<dim3(4, 64, 2),  tb, 0, stream>>>(Wk, Wv, wqkvt + (size_t)2048 * 2048,
                                            wqkvt + (size_t)2176 * 2048, 2048, 128);

  gemm_nt<3><<<dim3(18, 32), 256, 0, stream>>>(xb, wqkvt, bq, bk, bv,
                                               qb, kbuf, vtb, 4096, 2304, 2048, qscale);
  flash_mqa<<<dim3(32, 8, 2), 256, 0, stream>>>(qb, kbuf, vtb, ob);
  gemm_nt<1><<<dim3(16, 32), 256, 0, stream>>>(ob, wot, bo, nullptr, nullptr,
                                               out, nullptr, nullptr, 4096, 2048, 2048, 1.0f);
}

// Round 12
// 284.795 us; speedup vs baseline: 1.0203x; 1.0100x over previous
//
#include <hip/hip_runtime.h>

// MQA forward on MI355X (gfx950), bf16 MFMA path.
// B=2, S=2048, D_MODEL=2048, H=16, HEAD_DIM=128 (MQA: K/V shared across heads).
// R2: T2 XOR-swizzle in flash (bank conflicts 9.1e7 -> 0; 290 -> 191 us).
// R5: direct-global K/V frags: -87%. REVERTED.
// R6: softmax-lite (deferred l-sum, T13 defer-max): 187 -> 167 us.
// R7: swapped-operand flash (lane owns one q-row): 167 -> 139 us.
// R8: cvt_pk inline asm: REVERTED (m240). exp2-direct kept.
// R9: 2 heads per block: 139 -> 132.6 us.
// R10: K/V frag sharing across heads: REVERTED (VALU-bound, not LDS-BW).
// R11: GEMM 2-phase dbuf: null (m218 drain-0 == 1-phase). Reverted to single buf.
// R12: GEMM 256x128 tile / 8 waves (staging bytes per MFMA -27%, barriers/MFMA -50%,
//      per-wave code unchanged); converts merged into one launch.

typedef __attribute__((ext_vector_type(8))) short short8;
typedef __attribute__((ext_vector_type(4))) float f32x4;
typedef __attribute__((ext_vector_type(4))) unsigned int uint4v;

__device__ __forceinline__ unsigned short f2bf(float f) {
  unsigned int u = __float_as_uint(f);
  u += 0x7FFF + ((u >> 16) & 1);   // RNE
  return (unsigned short)(u >> 16);
}

__device__ __forceinline__ unsigned int pk2(float a, float b) {
  return (unsigned int)f2bf(a) | ((unsigned int)f2bf(b) << 16);
}

// async global->LDS 16B: dst must be wave-uniform (HW adds lane*16)
__device__ __forceinline__ void gll16(const void* g, void* lds) {
  __builtin_amdgcn_global_load_lds(
      (const __attribute__((address_space(1))) unsigned int*)g,
      (__attribute__((address_space(3))) unsigned int*)lds, 16, 0, 0);
}

// ---------------- merged prep: x->bf16 + 4 weight transposes, one launch ----------------
// blocks [0,4096): cvtk; [4096,12288): Wq/Wo transpose (64x64 each);
// [12288,12800): Wk/Wv transpose (4x64 each). All 256 threads.
__global__ __launch_bounds__(256)
void prep(const float* __restrict__ x, unsigned short* __restrict__ xb,
          const float* __restrict__ Wq, const float* __restrict__ Wo,
          const float* __restrict__ Wk, const float* __restrict__ Wv,
          unsigned short* __restrict__ wqkvt, unsigned short* __restrict__ wot) {
  __shared__ float tile[32][33];
  const int bid = blockIdx.x;
  const int t = threadIdx.x;

  if (bid < 4096) {
    int i = bid * 256 + t;
    const int stride = 4096 * 256;
    #pragma unroll
    for (int rep = 0; rep < 2; ++rep, i += stride) {
      float4 v = reinterpret_cast<const float4*>(x)[i];
      ushort4 o;
      o.x = f2bf(v.x); o.y = f2bf(v.y); o.z = f2bf(v.z); o.w = f2bf(v.w);
      reinterpret_cast<ushort4*>(xb)[i] = o;
    }
    return;
  }

  const float* W;
  unsigned short* Wt;
  int K = 2048, N, bx, by;
  if (bid < 12288) {
    int r = bid - 4096;
    int z = r >> 12, rr = r & 4095;
    bx = rr & 63; by = rr >> 6; N = 2048;
    W = z ? Wo : Wq;
    Wt = z ? wot : wqkvt;
  } else {
    int r = bid - 12288;
    int z = r >> 8, rr = r & 255;
    bx = rr & 3; by = rr >> 2; N = 128;
    W = z ? Wv : Wk;
    Wt = wqkvt + (size_t)(z ? 2176 : 2048) * 2048;
  }
  const int tx = t & 31, ty = t >> 5;
  const int n0 = bx * 32, k0 = by * 32;
  #pragma unroll
  for (int i = 0; i < 32; i += 8)
    tile[ty + i][tx] = W[(size_t)(k0 + ty + i) * N + n0 + tx];
  __syncthreads();
  #pragma unroll
  for (int i = 0; i < 32; i += 8)
    Wt[(size_t)(n0 + ty + i) * K + k0 + tx] = f2bf(tile[tx][ty + i]);
}

// ---------------- GEMM: C = A[M][K] @ Bt[N][K]^T + bias ----------------
// 256x128 tile, BK=64, 512 threads = 8 waves (4M x 2N of 64x64 each).
// Per-wave inner code identical to the validated 128x128/4-wave kernel.
// LDS 48KB single-buffer -> 2 blocks/CU (launch_bounds caps VGPR at 128).
// MODE 1: f32 out C[M][N] (+b0)
// MODE 3: fused QKV epilogue (N=2304): col<2048 -> qb bf16 (acc+b0)*cmul;
//         col<2176 -> kbuf bf16 (+b1); else -> vt transposed bf16 (+b2)
template <int MODE>
__global__ __launch_bounds__(512, 4)
void gemm_nt(const unsigned short* __restrict__ A, const unsigned short* __restrict__ Bt,
             const float* __restrict__ b0, const float* __restrict__ b1,
             const float* __restrict__ b2,
             void* __restrict__ C, unsigned short* __restrict__ C2,
             unsigned short* __restrict__ C3, int M, int N, int K, float cmul) {
  __shared__ unsigned short lA[256 * 64];   // 32KB
  __shared__ unsigned short lB[128 * 64];   // 16KB
  const int t = threadIdx.x;
  const int lane = t & 63;
  const int w = t >> 6;
  const int wr = w >> 1, wc = w & 1;        // wr in [0,4), wc in [0,2)
  const int r15 = lane & 15, g4 = lane >> 4;
  const int tileM = blockIdx.y * 256;
  const int tileN = blockIdx.x * 128;

  f32x4 acc[4][4];
  #pragma unroll
  for (int i = 0; i < 4; i++)
    #pragma unroll
    for (int j = 0; j < 4; j++) acc[i][j] = (f32x4){0.f, 0.f, 0.f, 0.f};

  const int nkt = K >> 6;
  for (int kt = 0; kt < nkt; ++kt) {
    const int k0 = kt * 64;
    // stage A: 256 rows x 64 cols = 2048 granules of 16B, 4 per thread
    #pragma unroll
    for (int i = 0; i < 4; ++i) {
      int flat = i * 512 + t;
      int row = flat >> 3, gc = flat & 7;
      unsigned lb = (unsigned)(i * 512 + w * 64) * 16;
      gll16(A + (size_t)(tileM + row) * K + k0 + gc * 8, (char*)lA + lb);
    }
    // stage B: 128 rows x 64 cols = 1024 granules, 2 per thread
    #pragma unroll
    for (int i = 0; i < 2; ++i) {
      int flat = i * 512 + t;
      int row = flat >> 3, gc = flat & 7;
      unsigned lb = (unsigned)(i * 512 + w * 64) * 16;
      gll16(Bt + (size_t)(tileN + row) * K + k0 + gc * 8, (char*)lB + lb);
    }
    asm volatile("s_waitcnt vmcnt(0)" ::: "memory");
    __builtin_amdgcn_s_barrier();
    asm volatile("" ::: "memory");

    #pragma unroll
    for (int kk = 0; kk < 2; ++kk) {
      short8 af[4], bf[4];
      #pragma unroll
      for (int mt = 0; mt < 4; ++mt)
        af[mt] = *reinterpret_cast<const short8*>(&lA[(wr * 64 + mt * 16 + r15) * 64 + kk * 32 + g4 * 8]);
      #pragma unroll
      for (int nt = 0; nt < 4; ++nt)
        bf[nt] = *reinterpret_cast<const short8*>(&lB[(wc * 64 + nt * 16 + r15) * 64 + kk * 32 + g4 * 8]);
      #pragma unroll
      for (int mt = 0; mt < 4; ++mt)
        #pragma unroll
        for (int nt = 0; nt < 4; ++nt)
          acc[mt][nt] = __builtin_amdgcn_mfma_f32_16x16x32_bf16(af[mt], bf[nt], acc[mt][nt], 0, 0, 0);
    }
    asm volatile("" ::: "memory");
    __builtin_amdgcn_s_barrier();   // all waves done reading before restage
  }

  // epilogue: C/D layout col=lane&15, row=(lane>>4)*4+reg
  #pragma unroll
  for (int mt = 0; mt < 4; ++mt) {
    #pragma unroll
    for (int nt = 0; nt < 4; ++nt) {
      int col = tileN + wc * 64 + nt * 16 + r15;
      #pragma unroll
      for (int r = 0; r < 4; ++r) {
        int row = tileM + wr * 64 + mt * 16 + g4 * 4 + r;
        float v = acc[mt][nt][r];
        if (MODE == 1) {
          ((float*)C)[(size_t)row * N + col] = v + b0[col];
        } else {
          if (col < 2048) {
            ((unsigned short*)C)[(size_t)row * 2048 + col] = f2bf((v + b0[col]) * cmul);
          } else if (col < 2176) {
            int dd = col - 2048;
            C2[(size_t)row * 128 + dd] = f2bf(v + b1[dd]);
          } else {
            int dd = col - 2176;
            int bb = row >> 11, s = row & 2047;
            C3[((size_t)bb * 128 + dd) * 2048 + s] = f2bf(v + b2[dd]);  // v^T [b][d][s]
          }
        }
      }
    }
  }
}

// ---------------- flash attention (MQA), swapped operands, 2 heads/block (R9) ----------------
// grid (S/64, H/2, B), 256 threads = 4 waves; wave owns 16 q rows (q = r15 per lane).
// qb [B*S][2048] bf16 (pre-scaled by log2(e)/sqrt(d)), kb [B*S][128] bf16,
// vt [B][128][S] bf16, ob [B*S][2048] bf16
// QK^T = mfma(K,Q): D[kv][q]; softmax lane-local (q=r15); P=exp2(s'-m').
// PV  = mfma(V^T,P^T): D[d][q]; rescale lane-local.
// 2 heads share the staged K/V tile (MQA) -> stage/barrier cost amortized 2x.
__global__ __launch_bounds__(256)
void flash_mqa(const unsigned short* __restrict__ qb, const unsigned short* __restrict__ kb,
               const unsigned short* __restrict__ vt, unsigned short* __restrict__ ob) {
  __shared__ unsigned short lK[2][64 * 128];   // [kv][d], swizzled
  __shared__ unsigned short lV[2][128 * 64];   // [d][kv], swizzled
  __shared__ unsigned short lP[4][16 * 64];    // per-wave [q][kv], granule-swizzled

  const int t = threadIdx.x;
  const int lane = t & 63;
  const int w = t >> 6;
  const int r15 = lane & 15, g4 = lane >> 4;
  const int qt = blockIdx.x, hy = blockIdx.y, b = blockIdx.z;
  const int q0 = qt * 64 + w * 16;

  // persistent Q B-frags for 2 heads: row q=r15, k = g4*8
  short8 qf[2][4];
  const size_t qrow = (size_t)(b * 2048 + q0 + r15);
  #pragma unroll
  for (int hh = 0; hh < 2; ++hh)
    #pragma unroll
    for (int kk = 0; kk < 4; ++kk)
      qf[hh][kk] = *reinterpret_cast<const short8*>(
          &qb[qrow * 2048 + (hy * 2 + hh) * 128 + kk * 32 + g4 * 8]);

  f32x4 oacc[2][8];   // O^T: oacc[hh][ot][r] -> d = ot*16+g4*4+r, q = r15
  #pragma unroll
  for (int hh = 0; hh < 2; ++hh)
    #pragma unroll
    for (int i = 0; i < 8; i++) oacc[hh][i] = (f32x4){0.f, 0.f, 0.f, 0.f};
  float m_q[2] = {-1e30f, -1e30f}, l_q[2] = {0.f, 0.f};  // log2 units

  const unsigned short* kbase = kb + (size_t)b * 2048 * 128;
  const unsigned short* vbase = vt + (size_t)b * 128 * 2048;

  auto stage = [&](int buf, int kv0) {
    #pragma unroll
    for (int i = 0; i < 4; ++i) {
      int flat = i * 256 + t;
      unsigned lb = (unsigned)(i * 256 + w * 64) * 16;
      { int row = flat >> 4, gc = flat & 15;
        gll16(kbase + (size_t)(kv0 + row) * 128 + ((gc ^ (row & 15)) << 3), (char*)lK[buf] + lb); }
      { int row = flat >> 3, gc = flat & 7;
        gll16(vbase + (size_t)row * 2048 + kv0 + ((gc ^ (row & 7)) << 3), (char*)lV[buf] + lb); }
    }
  };

  stage(0, 0);
  int cur = 0;
  for (int it = 0; it < 32; ++it) {
    if (it < 31) {
      stage(cur ^ 1, (it + 1) * 64);
      asm volatile("s_waitcnt vmcnt(8)" ::: "memory");  // current tile's 8 loads done
    } else {
      asm volatile("s_waitcnt vmcnt(0)" ::: "memory");
    }
    __builtin_amdgcn_s_barrier();
    asm volatile("" ::: "memory");

    const unsigned short* cK = lK[cur];
    const unsigned short* cV = lV[cur];

    #pragma unroll
    for (int hh = 0; hh < 2; ++hh) {
      // ---- QK^T swapped: s[ct] = K_sub(ct) x Q -> D[kv][q] (log2-scaled) ----
      f32x4 s[4];
      #pragma unroll
      for (int ct = 0; ct < 4; ct++) s[ct] = (f32x4){0.f, 0.f, 0.f, 0.f};
      #pragma unroll
      for (int kk = 0; kk < 4; ++kk) {
        #pragma unroll
        for (int ct = 0; ct < 4; ++ct) {
          const int krow = ct * 16 + r15;
          const int kg = (kk * 4 + g4) ^ (krow & 15);
          short8 kf = *reinterpret_cast<const short8*>(&cK[krow * 128 + kg * 8]);
          s[ct] = __builtin_amdgcn_mfma_f32_16x16x32_bf16(kf, qf[hh][kk], s[ct], 0, 0, 0);
        }
      }

      // ---- softmax: lane owns q=r15 with 16 kv values ----
      float mx = s[0][0];
      #pragma unroll
      for (int ct = 0; ct < 4; ++ct)
        #pragma unroll
        for (int r = 0; r < 4; ++r) mx = fmaxf(mx, s[ct][r]);
      mx = fmaxf(mx, __shfl_xor(mx, 16));
      mx = fmaxf(mx, __shfl_xor(mx, 32));
      // T13 defer-max: rescale only when growth > 8/ln2 (P bounded by e^8)
      if (__any(mx > m_q[hh] + 11.5416f)) {
        float mn = fmaxf(m_q[hh], mx);
        float rf = exp2f(m_q[hh] - mn);   // lane-local (q=r15)
        m_q[hh] = mn;
        l_q[hh] *= rf;
        #pragma unroll
        for (int ot = 0; ot < 8; ++ot)
          #pragma unroll
          for (int r = 0; r < 4; ++r) oacc[hh][ot][r] *= rf;
      }
      // ---- P = exp2(s-m), pack, b64 write to lP (granule ^ r15) ----
      #pragma unroll
      for (int ct = 0; ct < 4; ++ct) {
        float p0 = exp2f(s[ct][0] - m_q[hh]);
        float p1 = exp2f(s[ct][1] - m_q[hh]);
        float p2 = exp2f(s[ct][2] - m_q[hh]);
        float p3 = exp2f(s[ct][3] - m_q[hh]);
        l_q[hh] += (p0 + p1) + (p2 + p3);
        const int gi = (ct * 4 + g4) ^ r15;
        *reinterpret_cast<uint2*>(&lP[w][r15 * 64 + gi * 4]) = make_uint2(pk2(p0, p1), pk2(p2, p3));
      }

      // ---- PV swapped: oacc = V^T_sub(ot) x P^T -> D[d][q] ----
      #pragma unroll
      for (int kk = 0; kk < 2; ++kk) {
        const int gA = (kk * 8 + g4 * 2) ^ r15;
        const int gB = (kk * 8 + g4 * 2 + 1) ^ r15;
        const uint2 wa = *reinterpret_cast<const uint2*>(&lP[w][r15 * 64 + gA * 4]);
        const uint2 wb = *reinterpret_cast<const uint2*>(&lP[w][r15 * 64 + gB * 4]);
        uint4v pw = {wa.x, wa.y, wb.x, wb.y};
        short8 pf = __builtin_bit_cast(short8, pw);
        #pragma unroll
        for (int ot = 0; ot < 8; ++ot) {
          const int vrow = ot * 16 + r15;
          const int vg = (kk * 4 + g4) ^ (vrow & 7);
          short8 vf = *reinterpret_cast<const short8*>(&cV[vrow * 64 + vg * 8]);
          oacc[hh][ot] = __builtin_amdgcn_mfma_f32_16x16x32_bf16(vf, pf, oacc[hh][ot], 0, 0, 0);
        }
      }
    }

    asm volatile("" ::: "memory");
    __builtin_amdgcn_s_barrier();   // all waves done reading buf[cur] before restage
    cur ^= 1;
  }

  // epilogue: cross-lane l reduce (kv partials live on lanes r15, r15+16, +32, +48)
  #pragma unroll
  for (int hh = 0; hh < 2; ++hh) {
    float l = l_q[hh];
    l += __shfl_xor(l, 16);
    l += __shfl_xor(l, 32);
    const float inv = 1.0f / l;
    const int row = q0 + r15;
    const size_t base = ((size_t)(b * 2048 + row)) * 2048 + (hy * 2 + hh) * 128;
    #pragma unroll
    for (int ot = 0; ot < 8; ++ot) {
      uint2 pw = make_uint2(pk2(oacc[hh][ot][0] * inv, oacc[hh][ot][1] * inv),
                            pk2(oacc[hh][ot][2] * inv, oacc[hh][ot][3] * inv));
      *reinterpret_cast<uint2*>(&ob[base + ot * 16 + g4 * 4]) = pw;
    }
  }
}

extern "C" void kernel_launch(void* const* d_in, const int* in_sizes, int n_in,
                              void* d_out, int out_size, void* d_ws, size_t ws_size,
                              hipStream_t stream) {
  const float* x  = (const float*)d_in[0];
  const float* Wq = (const float*)d_in[1];
  const float* bq = (const float*)d_in[2];
  const float* Wk = (const float*)d_in[3];
  const float* bk = (const float*)d_in[4];
  const float* Wv = (const float*)d_in[5];
  const float* bv = (const float*)d_in[6];
  const float* Wo = (const float*)d_in[7];
  const float* bo = (const float*)d_in[8];
  float* out = (float*)d_out;

  char* ws = (char*)d_ws;
  size_t off = 0;
  auto alloc = [&](size_t elems) {
    unsigned short* p = (unsigned short*)(ws + off);
    off += (elems * 2 + 255) & ~(size_t)255;
    return p;
  };
  unsigned short* xb    = alloc(8388608);   // x bf16 [4096][2048]
  unsigned short* qb    = alloc(8388608);   // q bf16 [4096][2048] (pre-scaled, log2 units)
  unsigned short* ob    = alloc(8388608);   // attn out bf16 [4096][2048]
  unsigned short* wqkvt = alloc(4718592);   // [Wq^T;Wk^T;Wv^T] [2304][2048]
  unsigned short* wot   = alloc(4194304);   // Wo^T [2048][2048]
  unsigned short* kbuf  = alloc(524288);    // k bf16 [4096][128]
  unsigned short* vtb   = alloc(524288);    // v^T bf16 [2][128][2048]

  // 1/sqrt(128) * log2(e): scores come out of QK^T already in log2 units
  const float qscale = 0.08838834764831845f * 1.44269504088896f;

  prep<<<12800, 256, 0, stream>>>(x, xb, Wq, Wo, Wk, Wv, wqkvt, wot);

  gemm_nt<3><<<dim3(18, 16), 512, 0, stream>>>(xb, wqkvt, bq, bk, bv,
                                               qb, kbuf, vtb, 4096, 2304, 2048, qscale);
  flash_mqa<<<dim3(32, 8, 2), 256, 0, stream>>>(qb, kbuf, vtb, ob);
  gemm_nt<1><<<dim3(16, 16), 512, 0, stream>>>(ob, wot, bo, nullptr, nullptr,
                                               out, nullptr, nullptr, 4096, 2048, 2048, 1.0f);
}

// Round 13
// 258.351 us; speedup vs baseline: 1.1247x; 1.1024x over previous
//
#include <hip/hip_runtime.h>

// MQA forward on MI355X (gfx950), bf16 MFMA path.
// B=2, S=2048, D_MODEL=2048, H=16, HEAD_DIM=128 (MQA: K/V shared across heads).
// R2: T2 XOR-swizzle in flash (bank conflicts 9.1e7 -> 0; 290 -> 191 us).
// R6: softmax-lite (deferred l-sum, T13 defer-max): 187 -> 167 us.
// R7: swapped-operand flash (lane owns one q-row): 167 -> 139 us.
// R8: cvt_pk asm REVERTED (m240); exp2-direct kept.
// R9: 2 heads per block: 139 -> 132.6 us.
// R10/R11: frag-sharing, GEMM dbuf: null/negative. REVERTED.
// R12: 256x128 GEMM: +1% only -> grids were 288/256 blocks = 1.1/CU (grid-starved,
//      m102 shape-curve effect).
// R13: GEMM tiles 128x64 -> grids 1152/1024 blocks (~4/CU), LDS 24KB (6/CU capacity).

typedef __attribute__((ext_vector_type(8))) short short8;
typedef __attribute__((ext_vector_type(4))) float f32x4;
typedef __attribute__((ext_vector_type(4))) unsigned int uint4v;

__device__ __forceinline__ unsigned short f2bf(float f) {
  unsigned int u = __float_as_uint(f);
  u += 0x7FFF + ((u >> 16) & 1);   // RNE
  return (unsigned short)(u >> 16);
}

__device__ __forceinline__ unsigned int pk2(float a, float b) {
  return (unsigned int)f2bf(a) | ((unsigned int)f2bf(b) << 16);
}

// async global->LDS 16B: dst must be wave-uniform (HW adds lane*16)
__device__ __forceinline__ void gll16(const void* g, void* lds) {
  __builtin_amdgcn_global_load_lds(
      (const __attribute__((address_space(1))) unsigned int*)g,
      (__attribute__((address_space(3))) unsigned int*)lds, 16, 0, 0);
}

// ---------------- merged prep: x->bf16 + 4 weight transposes, one launch ----------------
__global__ __launch_bounds__(256)
void prep(const float* __restrict__ x, unsigned short* __restrict__ xb,
          const float* __restrict__ Wq, const float* __restrict__ Wo,
          const float* __restrict__ Wk, const float* __restrict__ Wv,
          unsigned short* __restrict__ wqkvt, unsigned short* __restrict__ wot) {
  __shared__ float tile[32][33];
  const int bid = blockIdx.x;
  const int t = threadIdx.x;

  if (bid < 4096) {
    int i = bid * 256 + t;
    const int stride = 4096 * 256;
    #pragma unroll
    for (int rep = 0; rep < 2; ++rep, i += stride) {
      float4 v = reinterpret_cast<const float4*>(x)[i];
      ushort4 o;
      o.x = f2bf(v.x); o.y = f2bf(v.y); o.z = f2bf(v.z); o.w = f2bf(v.w);
      reinterpret_cast<ushort4*>(xb)[i] = o;
    }
    return;
  }

  const float* W;
  unsigned short* Wt;
  int K = 2048, N, bx, by;
  if (bid < 12288) {
    int r = bid - 4096;
    int z = r >> 12, rr = r & 4095;
    bx = rr & 63; by = rr >> 6; N = 2048;
    W = z ? Wo : Wq;
    Wt = z ? wot : wqkvt;
  } else {
    int r = bid - 12288;
    int z = r >> 8, rr = r & 255;
    bx = rr & 3; by = rr >> 2; N = 128;
    W = z ? Wv : Wk;
    Wt = wqkvt + (size_t)(z ? 2176 : 2048) * 2048;
  }
  const int tx = t & 31, ty = t >> 5;
  const int n0 = bx * 32, k0 = by * 32;
  #pragma unroll
  for (int i = 0; i < 32; i += 8)
    tile[ty + i][tx] = W[(size_t)(k0 + ty + i) * N + n0 + tx];
  __syncthreads();
  #pragma unroll
  for (int i = 0; i < 32; i += 8)
    Wt[(size_t)(n0 + ty + i) * K + k0 + tx] = f2bf(tile[tx][ty + i]);
}

// ---------------- GEMM: C = A[M][K] @ Bt[N][K]^T + bias ----------------
// 128x64 tile, BK=64, 256 threads = 4 waves (2M x 2N of 64x32 each).
// LDS 24KB -> 6 blocks/CU capacity; grids >=1024 blocks (~4/CU) restore TLP.
// MODE 1: f32 out C[M][N] (+b0)
// MODE 3: fused QKV epilogue (N=2304): col<2048 -> qb bf16 (acc+b0)*cmul;
//         col<2176 -> kbuf bf16 (+b1); else -> vt transposed bf16 (+b2)
template <int MODE>
__global__ __launch_bounds__(256)
void gemm_nt(const unsigned short* __restrict__ A, const unsigned short* __restrict__ Bt,
             const float* __restrict__ b0, const float* __restrict__ b1,
             const float* __restrict__ b2,
             void* __restrict__ C, unsigned short* __restrict__ C2,
             unsigned short* __restrict__ C3, int M, int N, int K, float cmul) {
  __shared__ unsigned short lA[128 * 64];   // 16KB
  __shared__ unsigned short lB[64 * 64];    // 8KB
  const int t = threadIdx.x;
  const int lane = t & 63;
  const int w = t >> 6;
  const int wr = w >> 1, wc = w & 1;
  const int r15 = lane & 15, g4 = lane >> 4;
  const int tileM = blockIdx.y * 128;
  const int tileN = blockIdx.x * 64;

  f32x4 acc[4][2];
  #pragma unroll
  for (int i = 0; i < 4; i++)
    #pragma unroll
    for (int j = 0; j < 2; j++) acc[i][j] = (f32x4){0.f, 0.f, 0.f, 0.f};

  const int nkt = K >> 6;
  for (int kt = 0; kt < nkt; ++kt) {
    const int k0 = kt * 64;
    // stage A: 128 rows x 8 granules = 1024, 4/thread
    #pragma unroll
    for (int i = 0; i < 4; ++i) {
      int flat = i * 256 + t;
      int row = flat >> 3, gc = flat & 7;
      unsigned lb = (unsigned)(i * 256 + w * 64) * 16;
      gll16(A + (size_t)(tileM + row) * K + k0 + gc * 8, (char*)lA + lb);
    }
    // stage B: 64 rows x 8 granules = 512, 2/thread
    #pragma unroll
    for (int i = 0; i < 2; ++i) {
      int flat = i * 256 + t;
      int row = flat >> 3, gc = flat & 7;
      unsigned lb = (unsigned)(i * 256 + w * 64) * 16;
      gll16(Bt + (size_t)(tileN + row) * K + k0 + gc * 8, (char*)lB + lb);
    }
    asm volatile("s_waitcnt vmcnt(0)" ::: "memory");
    __builtin_amdgcn_s_barrier();
    asm volatile("" ::: "memory");

    #pragma unroll
    for (int kk = 0; kk < 2; ++kk) {
      short8 af[4], bf[2];
      #pragma unroll
      for (int mt = 0; mt < 4; ++mt)
        af[mt] = *reinterpret_cast<const short8*>(&lA[(wr * 64 + mt * 16 + r15) * 64 + kk * 32 + g4 * 8]);
      #pragma unroll
      for (int nt = 0; nt < 2; ++nt)
        bf[nt] = *reinterpret_cast<const short8*>(&lB[(wc * 32 + nt * 16 + r15) * 64 + kk * 32 + g4 * 8]);
      #pragma unroll
      for (int mt = 0; mt < 4; ++mt)
        #pragma unroll
        for (int nt = 0; nt < 2; ++nt)
          acc[mt][nt] = __builtin_amdgcn_mfma_f32_16x16x32_bf16(af[mt], bf[nt], acc[mt][nt], 0, 0, 0);
    }
    asm volatile("" ::: "memory");
    __builtin_amdgcn_s_barrier();   // all waves done reading before restage
  }

  // epilogue: C/D layout col=lane&15, row=(lane>>4)*4+reg
  #pragma unroll
  for (int mt = 0; mt < 4; ++mt) {
    #pragma unroll
    for (int nt = 0; nt < 2; ++nt) {
      int col = tileN + wc * 32 + nt * 16 + r15;
      #pragma unroll
      for (int r = 0; r < 4; ++r) {
        int row = tileM + wr * 64 + mt * 16 + g4 * 4 + r;
        float v = acc[mt][nt][r];
        if (MODE == 1) {
          ((float*)C)[(size_t)row * N + col] = v + b0[col];
        } else {
          if (col < 2048) {
            ((unsigned short*)C)[(size_t)row * 2048 + col] = f2bf((v + b0[col]) * cmul);
          } else if (col < 2176) {
            int dd = col - 2048;
            C2[(size_t)row * 128 + dd] = f2bf(v + b1[dd]);
          } else {
            int dd = col - 2176;
            int bb = row >> 11, s = row & 2047;
            C3[((size_t)bb * 128 + dd) * 2048 + s] = f2bf(v + b2[dd]);  // v^T [b][d][s]
          }
        }
      }
    }
  }
}

// ---------------- flash attention (MQA), swapped operands, 2 heads/block (R9) ----------------
// grid (S/64, H/2, B), 256 threads = 4 waves; wave owns 16 q rows (q = r15 per lane).
// qb [B*S][2048] bf16 (pre-scaled by log2(e)/sqrt(d)), kb [B*S][128] bf16,
// vt [B][128][S] bf16, ob [B*S][2048] bf16
// QK^T = mfma(K,Q): D[kv][q]; softmax lane-local (q=r15); P=exp2(s'-m').
// PV  = mfma(V^T,P^T): D[d][q]; rescale lane-local.
// 2 heads share the staged K/V tile (MQA) -> stage/barrier cost amortized 2x.
__global__ __launch_bounds__(256)
void flash_mqa(const unsigned short* __restrict__ qb, const unsigned short* __restrict__ kb,
               const unsigned short* __restrict__ vt, unsigned short* __restrict__ ob) {
  __shared__ unsigned short lK[2][64 * 128];   // [kv][d], swizzled
  __shared__ unsigned short lV[2][128 * 64];   // [d][kv], swizzled
  __shared__ unsigned short lP[4][16 * 64];    // per-wave [q][kv], granule-swizzled

  const int t = threadIdx.x;
  const int lane = t & 63;
  const int w = t >> 6;
  const int r15 = lane & 15, g4 = lane >> 4;
  const int qt = blockIdx.x, hy = blockIdx.y, b = blockIdx.z;
  const int q0 = qt * 64 + w * 16;

  // persistent Q B-frags for 2 heads: row q=r15, k = g4*8
  short8 qf[2][4];
  const size_t qrow = (size_t)(b * 2048 + q0 + r15);
  #pragma unroll
  for (int hh = 0; hh < 2; ++hh)
    #pragma unroll
    for (int kk = 0; kk < 4; ++kk)
      qf[hh][kk] = *reinterpret_cast<const short8*>(
          &qb[qrow * 2048 + (hy * 2 + hh) * 128 + kk * 32 + g4 * 8]);

  f32x4 oacc[2][8];   // O^T: oacc[hh][ot][r] -> d = ot*16+g4*4+r, q = r15
  #pragma unroll
  for (int hh = 0; hh < 2; ++hh)
    #pragma unroll
    for (int i = 0; i < 8; i++) oacc[hh][i] = (f32x4){0.f, 0.f, 0.f, 0.f};
  float m_q[2] = {-1e30f, -1e30f}, l_q[2] = {0.f, 0.f};  // log2 units

  const unsigned short* kbase = kb + (size_t)b * 2048 * 128;
  const unsigned short* vbase = vt + (size_t)b * 128 * 2048;

  auto stage = [&](int buf, int kv0) {
    #pragma unroll
    for (int i = 0; i < 4; ++i) {
      int flat = i * 256 + t;
      unsigned lb = (unsigned)(i * 256 + w * 64) * 16;
      { int row = flat >> 4, gc = flat & 15;
        gll16(kbase + (size_t)(kv0 + row) * 128 + ((gc ^ (row & 15)) << 3), (char*)lK[buf] + lb); }
      { int row = flat >> 3, gc = flat & 7;
        gll16(vbase + (size_t)row * 2048 + kv0 + ((gc ^ (row & 7)) << 3), (char*)lV[buf] + lb); }
    }
  };

  stage(0, 0);
  int cur = 0;
  for (int it = 0; it < 32; ++it) {
    if (it < 31) {
      stage(cur ^ 1, (it + 1) * 64);
      asm volatile("s_waitcnt vmcnt(8)" ::: "memory");  // current tile's 8 loads done
    } else {
      asm volatile("s_waitcnt vmcnt(0)" ::: "memory");
    }
    __builtin_amdgcn_s_barrier();
    asm volatile("" ::: "memory");

    const unsigned short* cK = lK[cur];
    const unsigned short* cV = lV[cur];

    #pragma unroll
    for (int hh = 0; hh < 2; ++hh) {
      // ---- QK^T swapped: s[ct] = K_sub(ct) x Q -> D[kv][q] (log2-scaled) ----
      f32x4 s[4];
      #pragma unroll
      for (int ct = 0; ct < 4; ct++) s[ct] = (f32x4){0.f, 0.f, 0.f, 0.f};
      #pragma unroll
      for (int kk = 0; kk < 4; ++kk) {
        #pragma unroll
        for (int ct = 0; ct < 4; ++ct) {
          const int krow = ct * 16 + r15;
          const int kg = (kk * 4 + g4) ^ (krow & 15);
          short8 kf = *reinterpret_cast<const short8*>(&cK[krow * 128 + kg * 8]);
          s[ct] = __builtin_amdgcn_mfma_f32_16x16x32_bf16(kf, qf[hh][kk], s[ct], 0, 0, 0);
        }
      }

      // ---- softmax: lane owns q=r15 with 16 kv values ----
      float mx = s[0][0];
      #pragma unroll
      for (int ct = 0; ct < 4; ++ct)
        #pragma unroll
        for (int r = 0; r < 4; ++r) mx = fmaxf(mx, s[ct][r]);
      mx = fmaxf(mx, __shfl_xor(mx, 16));
      mx = fmaxf(mx, __shfl_xor(mx, 32));
      // T13 defer-max: rescale only when growth > 8/ln2 (P bounded by e^8)
      if (__any(mx > m_q[hh] + 11.5416f)) {
        float mn = fmaxf(m_q[hh], mx);
        float rf = exp2f(m_q[hh] - mn);   // lane-local (q=r15)
        m_q[hh] = mn;
        l_q[hh] *= rf;
        #pragma unroll
        for (int ot = 0; ot < 8; ++ot)
          #pragma unroll
          for (int r = 0; r < 4; ++r) oacc[hh][ot][r] *= rf;
      }
      // ---- P = exp2(s-m), pack, b64 write to lP (granule ^ r15) ----
      #pragma unroll
      for (int ct = 0; ct < 4; ++ct) {
        float p0 = exp2f(s[ct][0] - m_q[hh]);
        float p1 = exp2f(s[ct][1] - m_q[hh]);
        float p2 = exp2f(s[ct][2] - m_q[hh]);
        float p3 = exp2f(s[ct][3] - m_q[hh]);
        l_q[hh] += (p0 + p1) + (p2 + p3);
        const int gi = (ct * 4 + g4) ^ r15;
        *reinterpret_cast<uint2*>(&lP[w][r15 * 64 + gi * 4]) = make_uint2(pk2(p0, p1), pk2(p2, p3));
      }

      // ---- PV swapped: oacc = V^T_sub(ot) x P^T -> D[d][q] ----
      #pragma unroll
      for (int kk = 0; kk < 2; ++kk) {
        const int gA = (kk * 8 + g4 * 2) ^ r15;
        const int gB = (kk * 8 + g4 * 2 + 1) ^ r15;
        const uint2 wa = *reinterpret_cast<const uint2*>(&lP[w][r15 * 64 + gA * 4]);
        const uint2 wb = *reinterpret_cast<const uint2*>(&lP[w][r15 * 64 + gB * 4]);
        uint4v pw = {wa.x, wa.y, wb.x, wb.y};
        short8 pf = __builtin_bit_cast(short8, pw);
        #pragma unroll
        for (int ot = 0; ot < 8; ++ot) {
          const int vrow = ot * 16 + r15;
          const int vg = (kk * 4 + g4) ^ (vrow & 7);
          short8 vf = *reinterpret_cast<const short8*>(&cV[vrow * 64 + vg * 8]);
          oacc[hh][ot] = __builtin_amdgcn_mfma_f32_16x16x32_bf16(vf, pf, oacc[hh][ot], 0, 0, 0);
        }
      }
    }

    asm volatile("" ::: "memory");
    __builtin_amdgcn_s_barrier();   // all waves done reading buf[cur] before restage
    cur ^= 1;
  }

  // epilogue: cross-lane l reduce (kv partials live on lanes r15, r15+16, +32, +48)
  #pragma unroll
  for (int hh = 0; hh < 2; ++hh) {
    float l = l_q[hh];
    l += __shfl_xor(l, 16);
    l += __shfl_xor(l, 32);
    const float inv = 1.0f / l;
    const int row = q0 + r15;
    const size_t base = ((size_t)(b * 2048 + row)) * 2048 + (hy * 2 + hh) * 128;
    #pragma unroll
    for (int ot = 0; ot < 8; ++ot) {
      uint2 pw = make_uint2(pk2(oacc[hh][ot][0] * inv, oacc[hh][ot][1] * inv),
                            pk2(oacc[hh][ot][2] * inv, oacc[hh][ot][3] * inv));
      *reinterpret_cast<uint2*>(&ob[base + ot * 16 + g4 * 4]) = pw;
    }
  }
}

extern "C" void kernel_launch(void* const* d_in, const int* in_sizes, int n_in,
                              void* d_out, int out_size, void* d_ws, size_t ws_size,
                              hipStream_t stream) {
  const float* x  = (const float*)d_in[0];
  const float* Wq = (const float*)d_in[1];
  const float* bq = (const float*)d_in[2];
  const float* Wk = (const float*)d_in[3];
  const float* bk = (const float*)d_in[4];
  const float* Wv = (const float*)d_in[5];
  const float* bv = (const float*)d_in[6];
  const float* Wo = (const float*)d_in[7];
  const float* bo = (const float*)d_in[8];
  float* out = (float*)d_out;

  char* ws = (char*)d_ws;
  size_t off = 0;
  auto alloc = [&](size_t elems) {
    unsigned short* p = (unsigned short*)(ws + off);
    off += (elems * 2 + 255) & ~(size_t)255;
    return p;
  };
  unsigned short* xb    = alloc(8388608);   // x bf16 [4096][2048]
  unsigned short* qb    = alloc(8388608);   // q bf16 [4096][2048] (pre-scaled, log2 units)
  unsigned short* ob    = alloc(8388608);   // attn out bf16 [4096][2048]
  unsigned short* wqkvt = alloc(4718592);   // [Wq^T;Wk^T;Wv^T] [2304][2048]
  unsigned short* wot   = alloc(4194304);   // Wo^T [2048][2048]
  unsigned short* kbuf  = alloc(524288);    // k bf16 [4096][128]
  unsigned short* vtb   = alloc(524288);    // v^T bf16 [2][128][2048]

  // 1/sqrt(128) * log2(e): scores come out of QK^T already in log2 units
  const float qscale = 0.08838834764831845f * 1.44269504088896f;

  prep<<<12800, 256, 0, stream>>>(x, xb, Wq, Wo, Wk, Wv, wqkvt, wot);

  gemm_nt<3><<<dim3(36, 32), 256, 0, stream>>>(xb, wqkvt, bq, bk, bv,
                                               qb, kbuf, vtb, 4096, 2304, 2048, qscale);
  flash_mqa<<<dim3(32, 8, 2), 256, 0, stream>>>(qb, kbuf, vtb, ob);
  gemm_nt<1><<<dim3(32, 32), 256, 0, stream>>>(ob, wot, bo, nullptr, nullptr,
                                               out, nullptr, nullptr, 4096, 2048, 2048, 1.0f);
}

// Round 14
// 246.115 us; speedup vs baseline: 1.1806x; 1.0497x over previous
//
#include <hip/hip_runtime.h>

// MQA forward on MI355X (gfx950), bf16 MFMA path.
// B=2, S=2048, D_MODEL=2048, H=16, HEAD_DIM=128 (MQA: K/V shared across heads).
// R2: T2 XOR-swizzle in flash (bank conflicts 9.1e7 -> 0; 290 -> 191 us).
// R6: softmax-lite (deferred l-sum, T13 defer-max): 187 -> 167 us.
// R7: swapped-operand flash (lane owns one q-row): 167 -> 139 us.
// R8: cvt_pk asm REVERTED (m240); exp2-direct kept.
// R9: 2 heads per block: 139 -> 132.6 us.
// R10/R11: frag-sharing, GEMM dbuf: null/negative. REVERTED.
// R12/R13: GEMM grid-starvation found and fixed (128x64 tiles, ~4 blocks/CU):
//          GEMM half 129 -> 103 us; total 284.8 -> 258.4.
// R14: flash 8 waves x 512 thr, QBLK=128, 1 head/block: 16 waves/CU (was 8) --
//      doubles TLP coverage of barriers/VALU; staging amortized over 8 waves.

typedef __attribute__((ext_vector_type(8))) short short8;
typedef __attribute__((ext_vector_type(4))) float f32x4;
typedef __attribute__((ext_vector_type(4))) unsigned int uint4v;

__device__ __forceinline__ unsigned short f2bf(float f) {
  unsigned int u = __float_as_uint(f);
  u += 0x7FFF + ((u >> 16) & 1);   // RNE
  return (unsigned short)(u >> 16);
}

__device__ __forceinline__ unsigned int pk2(float a, float b) {
  return (unsigned int)f2bf(a) | ((unsigned int)f2bf(b) << 16);
}

// async global->LDS 16B: dst must be wave-uniform (HW adds lane*16)
__device__ __forceinline__ void gll16(const void* g, void* lds) {
  __builtin_amdgcn_global_load_lds(
      (const __attribute__((address_space(1))) unsigned int*)g,
      (__attribute__((address_space(3))) unsigned int*)lds, 16, 0, 0);
}

// ---------------- merged prep: x->bf16 + 4 weight transposes, one launch ----------------
__global__ __launch_bounds__(256)
void prep(const float* __restrict__ x, unsigned short* __restrict__ xb,
          const float* __restrict__ Wq, const float* __restrict__ Wo,
          const float* __restrict__ Wk, const float* __restrict__ Wv,
          unsigned short* __restrict__ wqkvt, unsigned short* __restrict__ wot) {
  __shared__ float tile[32][33];
  const int bid = blockIdx.x;
  const int t = threadIdx.x;

  if (bid < 4096) {
    int i = bid * 256 + t;
    const int stride = 4096 * 256;
    #pragma unroll
    for (int rep = 0; rep < 2; ++rep, i += stride) {
      float4 v = reinterpret_cast<const float4*>(x)[i];
      ushort4 o;
      o.x = f2bf(v.x); o.y = f2bf(v.y); o.z = f2bf(v.z); o.w = f2bf(v.w);
      reinterpret_cast<ushort4*>(xb)[i] = o;
    }
    return;
  }

  const float* W;
  unsigned short* Wt;
  int K = 2048, N, bx, by;
  if (bid < 12288) {
    int r = bid - 4096;
    int z = r >> 12, rr = r & 4095;
    bx = rr & 63; by = rr >> 6; N = 2048;
    W = z ? Wo : Wq;
    Wt = z ? wot : wqkvt;
  } else {
    int r = bid - 12288;
    int z = r >> 8, rr = r & 255;
    bx = rr & 3; by = rr >> 2; N = 128;
    W = z ? Wv : Wk;
    Wt = wqkvt + (size_t)(z ? 2176 : 2048) * 2048;
  }
  const int tx = t & 31, ty = t >> 5;
  const int n0 = bx * 32, k0 = by * 32;
  #pragma unroll
  for (int i = 0; i < 32; i += 8)
    tile[ty + i][tx] = W[(size_t)(k0 + ty + i) * N + n0 + tx];
  __syncthreads();
  #pragma unroll
  for (int i = 0; i < 32; i += 8)
    Wt[(size_t)(n0 + ty + i) * K + k0 + tx] = f2bf(tile[tx][ty + i]);
}

// ---------------- GEMM: C = A[M][K] @ Bt[N][K]^T + bias ----------------
// 128x64 tile, BK=64, 256 threads = 4 waves (2M x 2N of 64x32 each).
// LDS 24KB; grids >=1024 blocks (~4/CU) for TLP (R13).
// MODE 1: f32 out C[M][N] (+b0)
// MODE 3: fused QKV epilogue (N=2304): col<2048 -> qb bf16 (acc+b0)*cmul;
//         col<2176 -> kbuf bf16 (+b1); else -> vt transposed bf16 (+b2)
template <int MODE>
__global__ __launch_bounds__(256)
void gemm_nt(const unsigned short* __restrict__ A, const unsigned short* __restrict__ Bt,
             const float* __restrict__ b0, const float* __restrict__ b1,
             const float* __restrict__ b2,
             void* __restrict__ C, unsigned short* __restrict__ C2,
             unsigned short* __restrict__ C3, int M, int N, int K, float cmul) {
  __shared__ unsigned short lA[128 * 64];   // 16KB
  __shared__ unsigned short lB[64 * 64];    // 8KB
  const int t = threadIdx.x;
  const int lane = t & 63;
  const int w = t >> 6;
  const int wr = w >> 1, wc = w & 1;
  const int r15 = lane & 15, g4 = lane >> 4;
  const int tileM = blockIdx.y * 128;
  const int tileN = blockIdx.x * 64;

  f32x4 acc[4][2];
  #pragma unroll
  for (int i = 0; i < 4; i++)
    #pragma unroll
    for (int j = 0; j < 2; j++) acc[i][j] = (f32x4){0.f, 0.f, 0.f, 0.f};

  const int nkt = K >> 6;
  for (int kt = 0; kt < nkt; ++kt) {
    const int k0 = kt * 64;
    #pragma unroll
    for (int i = 0; i < 4; ++i) {
      int flat = i * 256 + t;
      int row = flat >> 3, gc = flat & 7;
      unsigned lb = (unsigned)(i * 256 + w * 64) * 16;
      gll16(A + (size_t)(tileM + row) * K + k0 + gc * 8, (char*)lA + lb);
    }
    #pragma unroll
    for (int i = 0; i < 2; ++i) {
      int flat = i * 256 + t;
      int row = flat >> 3, gc = flat & 7;
      unsigned lb = (unsigned)(i * 256 + w * 64) * 16;
      gll16(Bt + (size_t)(tileN + row) * K + k0 + gc * 8, (char*)lB + lb);
    }
    asm volatile("s_waitcnt vmcnt(0)" ::: "memory");
    __builtin_amdgcn_s_barrier();
    asm volatile("" ::: "memory");

    #pragma unroll
    for (int kk = 0; kk < 2; ++kk) {
      short8 af[4], bf[2];
      #pragma unroll
      for (int mt = 0; mt < 4; ++mt)
        af[mt] = *reinterpret_cast<const short8*>(&lA[(wr * 64 + mt * 16 + r15) * 64 + kk * 32 + g4 * 8]);
      #pragma unroll
      for (int nt = 0; nt < 2; ++nt)
        bf[nt] = *reinterpret_cast<const short8*>(&lB[(wc * 32 + nt * 16 + r15) * 64 + kk * 32 + g4 * 8]);
      #pragma unroll
      for (int mt = 0; mt < 4; ++mt)
        #pragma unroll
        for (int nt = 0; nt < 2; ++nt)
          acc[mt][nt] = __builtin_amdgcn_mfma_f32_16x16x32_bf16(af[mt], bf[nt], acc[mt][nt], 0, 0, 0);
    }
    asm volatile("" ::: "memory");
    __builtin_amdgcn_s_barrier();
  }

  // epilogue: C/D layout col=lane&15, row=(lane>>4)*4+reg
  #pragma unroll
  for (int mt = 0; mt < 4; ++mt) {
    #pragma unroll
    for (int nt = 0; nt < 2; ++nt) {
      int col = tileN + wc * 32 + nt * 16 + r15;
      #pragma unroll
      for (int r = 0; r < 4; ++r) {
        int row = tileM + wr * 64 + mt * 16 + g4 * 4 + r;
        float v = acc[mt][nt][r];
        if (MODE == 1) {
          ((float*)C)[(size_t)row * N + col] = v + b0[col];
        } else {
          if (col < 2048) {
            ((unsigned short*)C)[(size_t)row * 2048 + col] = f2bf((v + b0[col]) * cmul);
          } else if (col < 2176) {
            int dd = col - 2048;
            C2[(size_t)row * 128 + dd] = f2bf(v + b1[dd]);
          } else {
            int dd = col - 2176;
            int bb = row >> 11, s = row & 2047;
            C3[((size_t)bb * 128 + dd) * 2048 + s] = f2bf(v + b2[dd]);  // v^T [b][d][s]
          }
        }
      }
    }
  }
}

// ---------------- flash attention (MQA): 8 waves, QBLK=128, 1 head/block ----------------
// grid (S/128, H, B), 512 threads = 8 waves; wave owns 16 q rows (q = r15 per lane).
// qb [B*S][2048] bf16 (pre-scaled by log2(e)/sqrt(d)), kb [B*S][128] bf16,
// vt [B][128][S] bf16, ob [B*S][2048] bf16
// QK^T = mfma(K,Q): D[kv][q]; softmax lane-local (q=r15); P=exp2(s'-m').
// PV  = mfma(V^T,P^T): D[d][q]; rescale lane-local.
// 16 waves/CU (2 blocks x 8): TLP hides barrier drains + VALU softmax.
// K/V staged once per block-iter for all 8 waves; dbuf, steady vmcnt(4).
__global__ __launch_bounds__(512, 4)
void flash_mqa(const unsigned short* __restrict__ qb, const unsigned short* __restrict__ kb,
               const unsigned short* __restrict__ vt, unsigned short* __restrict__ ob) {
  __shared__ unsigned short lK[2][64 * 128];   // [kv][d], swizzled
  __shared__ unsigned short lV[2][128 * 64];   // [d][kv], swizzled
  __shared__ unsigned short lP[8][16 * 64];    // per-wave [q][kv], granule-swizzled

  const int t = threadIdx.x;
  const int lane = t & 63;
  const int w = t >> 6;                 // 8 waves
  const int r15 = lane & 15, g4 = lane >> 4;
  const int qt = blockIdx.x, h = blockIdx.y, b = blockIdx.z;
  const int q0 = qt * 128 + w * 16;

  // persistent Q B-frags: row q=r15, k = g4*8
  short8 qf[4];
  const size_t qrow = (size_t)(b * 2048 + q0 + r15);
  #pragma unroll
  for (int kk = 0; kk < 4; ++kk)
    qf[kk] = *reinterpret_cast<const short8*>(&qb[qrow * 2048 + h * 128 + kk * 32 + g4 * 8]);

  f32x4 oacc[8];   // O^T: oacc[ot][r] -> d = ot*16+g4*4+r, q = r15
  #pragma unroll
  for (int i = 0; i < 8; i++) oacc[i] = (f32x4){0.f, 0.f, 0.f, 0.f};
  float m_q = -1e30f, l_q = 0.f;   // log2 units

  const unsigned short* kbase = kb + (size_t)b * 2048 * 128;
  const unsigned short* vbase = vt + (size_t)b * 128 * 2048;

  // 512 threads: K tile 1024 granules (2/thread), V tile 1024 granules (2/thread)
  auto stage = [&](int buf, int kv0) {
    #pragma unroll
    for (int i = 0; i < 2; ++i) {
      int flat = i * 512 + t;
      unsigned lb = (unsigned)(i * 512 + w * 64) * 16;
      { int row = flat >> 4, gc = flat & 15;
        gll16(kbase + (size_t)(kv0 + row) * 128 + ((gc ^ (row & 15)) << 3), (char*)lK[buf] + lb); }
      { int row = flat >> 3, gc = flat & 7;
        gll16(vbase + (size_t)row * 2048 + kv0 + ((gc ^ (row & 7)) << 3), (char*)lV[buf] + lb); }
    }
  };

  stage(0, 0);
  int cur = 0;
  for (int it = 0; it < 32; ++it) {
    if (it < 31) {
      stage(cur ^ 1, (it + 1) * 64);
      asm volatile("s_waitcnt vmcnt(4)" ::: "memory");  // current tile's 4 loads done
    } else {
      asm volatile("s_waitcnt vmcnt(0)" ::: "memory");
    }
    __builtin_amdgcn_s_barrier();
    asm volatile("" ::: "memory");

    const unsigned short* cK = lK[cur];
    const unsigned short* cV = lV[cur];

    // ---- QK^T swapped: s[ct] = K_sub(ct) x Q -> D[kv][q] (log2-scaled) ----
    f32x4 s[4];
    #pragma unroll
    for (int ct = 0; ct < 4; ct++) s[ct] = (f32x4){0.f, 0.f, 0.f, 0.f};
    #pragma unroll
    for (int kk = 0; kk < 4; ++kk) {
      #pragma unroll
      for (int ct = 0; ct < 4; ++ct) {
        const int krow = ct * 16 + r15;
        const int kg = (kk * 4 + g4) ^ (krow & 15);
        short8 kf = *reinterpret_cast<const short8*>(&cK[krow * 128 + kg * 8]);
        s[ct] = __builtin_amdgcn_mfma_f32_16x16x32_bf16(kf, qf[kk], s[ct], 0, 0, 0);
      }
    }

    // ---- softmax: lane owns q=r15 with 16 kv values ----
    float mx = s[0][0];
    #pragma unroll
    for (int ct = 0; ct < 4; ++ct)
      #pragma unroll
      for (int r = 0; r < 4; ++r) mx = fmaxf(mx, s[ct][r]);
    mx = fmaxf(mx, __shfl_xor(mx, 16));
    mx = fmaxf(mx, __shfl_xor(mx, 32));
    // T13 defer-max: rescale only when growth > 8/ln2 (P bounded by e^8)
    if (__any(mx > m_q + 11.5416f)) {
      float mn = fmaxf(m_q, mx);
      float rf = exp2f(m_q - mn);   // lane-local (q=r15)
      m_q = mn;
      l_q *= rf;
      #pragma unroll
      for (int ot = 0; ot < 8; ++ot)
        #pragma unroll
        for (int r = 0; r < 4; ++r) oacc[ot][r] *= rf;
    }
    // ---- P = exp2(s-m), pack, b64 write to lP (granule ^ r15) ----
    #pragma unroll
    for (int ct = 0; ct < 4; ++ct) {
      float p0 = exp2f(s[ct][0] - m_q);
      float p1 = exp2f(s[ct][1] - m_q);
      float p2 = exp2f(s[ct][2] - m_q);
      float p3 = exp2f(s[ct][3] - m_q);
      l_q += (p0 + p1) + (p2 + p3);
      const int gi = (ct * 4 + g4) ^ r15;
      *reinterpret_cast<uint2*>(&lP[w][r15 * 64 + gi * 4]) = make_uint2(pk2(p0, p1), pk2(p2, p3));
    }

    // ---- PV swapped: oacc = V^T_sub(ot) x P^T -> D[d][q] ----
    #pragma unroll
    for (int kk = 0; kk < 2; ++kk) {
      const int gA = (kk * 8 + g4 * 2) ^ r15;
      const int gB = (kk * 8 + g4 * 2 + 1) ^ r15;
      const uint2 wa = *reinterpret_cast<const uint2*>(&lP[w][r15 * 64 + gA * 4]);
      const uint2 wb = *reinterpret_cast<const uint2*>(&lP[w][r15 * 64 + gB * 4]);
      uint4v pw = {wa.x, wa.y, wb.x, wb.y};
      short8 pf = __builtin_bit_cast(short8, pw);
      #pragma unroll
      for (int ot = 0; ot < 8; ++ot) {
        const int vrow = ot * 16 + r15;
        const int vg = (kk * 4 + g4) ^ (vrow & 7);
        short8 vf = *reinterpret_cast<const short8*>(&cV[vrow * 64 + vg * 8]);
        oacc[ot] = __builtin_amdgcn_mfma_f32_16x16x32_bf16(vf, pf, oacc[ot], 0, 0, 0);
      }
    }

    asm volatile("" ::: "memory");
    __builtin_amdgcn_s_barrier();   // all waves done reading buf[cur] before restage
    cur ^= 1;
  }

  // epilogue: cross-lane l reduce (kv partials live on lanes r15, r15+16, +32, +48)
  float l = l_q;
  l += __shfl_xor(l, 16);
  l += __shfl_xor(l, 32);
  const float inv = 1.0f / l;
  const int row = q0 + r15;
  const size_t base = ((size_t)(b * 2048 + row)) * 2048 + h * 128;
  #pragma unroll
  for (int ot = 0; ot < 8; ++ot) {
    uint2 pw = make_uint2(pk2(oacc[ot][0] * inv, oacc[ot][1] * inv),
                          pk2(oacc[ot][2] * inv, oacc[ot][3] * inv));
    *reinterpret_cast<uint2*>(&ob[base + ot * 16 + g4 * 4]) = pw;
  }
}

extern "C" void kernel_launch(void* const* d_in, const int* in_sizes, int n_in,
                              void* d_out, int out_size, void* d_ws, size_t ws_size,
                              hipStream_t stream) {
  const float* x  = (const float*)d_in[0];
  const float* Wq = (const float*)d_in[1];
  const float* bq = (const float*)d_in[2];
  const float* Wk = (const float*)d_in[3];
  const float* bk = (const float*)d_in[4];
  const float* Wv = (const float*)d_in[5];
  const float* bv = (const float*)d_in[6];
  const float* Wo = (const float*)d_in[7];
  const float* bo = (const float*)d_in[8];
  float* out = (float*)d_out;

  char* ws = (char*)d_ws;
  size_t off = 0;
  auto alloc = [&](size_t elems) {
    unsigned short* p = (unsigned short*)(ws + off);
    off += (elems * 2 + 255) & ~(size_t)255;
    return p;
  };
  unsigned short* xb    = alloc(8388608);   // x bf16 [4096][2048]
  unsigned short* qb    = alloc(8388608);   // q bf16 [4096][2048] (pre-scaled, log2 units)
  unsigned short* ob    = alloc(8388608);   // attn out bf16 [4096][2048]
  unsigned short* wqkvt = alloc(4718592);   // [Wq^T;Wk^T;Wv^T] [2304][2048]
  unsigned short* wot   = alloc(4194304);   // Wo^T [2048][2048]
  unsigned short* kbuf  = alloc(524288);    // k bf16 [4096][128]
  unsigned short* vtb   = alloc(524288);    // v^T bf16 [2][128][2048]

  // 1/sqrt(128) * log2(e): scores come out of QK^T already in log2 units
  const float qscale = 0.08838834764831845f * 1.44269504088896f;

  prep<<<12800, 256, 0, stream>>>(x, xb, Wq, Wo, Wk, Wv, wqkvt, wot);

  gemm_nt<3><<<dim3(36, 32), 256, 0, stream>>>(xb, wqkvt, bq, bk, bv,
                                               qb, kbuf, vtb, 4096, 2304, 2048, qscale);
  flash_mqa<<<dim3(16, 16, 2), 512, 0, stream>>>(qb, kbuf, vtb, ob);
  gemm_nt<1><<<dim3(32, 32), 256, 0, stream>>>(ob, wot, bo, nullptr, nullptr,
                                               out, nullptr, nullptr, 4096, 2048, 2048, 1.0f);
}

// Round 15
// 241.952 us; speedup vs baseline: 1.2009x; 1.0172x over previous
//
#include <hip/hip_runtime.h>

// MQA forward on MI355X (gfx950), bf16 MFMA path.
// B=2, S=2048, D_MODEL=2048, H=16, HEAD_DIM=128 (MQA: K/V shared across heads).
// R2: T2 XOR-swizzle in flash (bank conflicts 9.1e7 -> 0; 290 -> 191 us).
// R6: softmax-lite (deferred l-sum, T13 defer-max): 187 -> 167 us.
// R7: swapped-operand flash (lane owns one q-row): 167 -> 139 us.
// R8: cvt_pk asm REVERTED (m240); exp2-direct kept.
// R9: 2 heads per block: 139 -> 132.6 us.
// R12/R13: GEMM grid-starvation fixed (128x64 tiles, ~4.5 blocks/CU): 284.8 -> 258.4.
// R14: flash 8 waves x 512 thr, QBLK=128: 16 waves/CU: 258.4 -> 246.1.
//      (16 waves/CU is the decomposition cap: 65536 q-rows / 16-per-wave = 4096 waves.)
// R15: flash truncating bf16 P/O pack (3 ops vs 9 per pair; VALU is the pipe at 55%);
//      GEMM XCD-aware block swizzle (T1; consecutive blocks share A-panel in XCD L2).

typedef __attribute__((ext_vector_type(8))) short short8;
typedef __attribute__((ext_vector_type(4))) float f32x4;
typedef __attribute__((ext_vector_type(4))) unsigned int uint4v;

__device__ __forceinline__ unsigned short f2bf(float f) {
  unsigned int u = __float_as_uint(f);
  u += 0x7FFF + ((u >> 16) & 1);   // RNE
  return (unsigned short)(u >> 16);
}

__device__ __forceinline__ unsigned int pk2(float a, float b) {
  return (unsigned int)f2bf(a) | ((unsigned int)f2bf(b) << 16);
}

// truncating pack: 3 VALU ops; rel err <= 2^-8 (vs 2^-9 RNE) -- used only on
// flash P/O hot path where VALU is the bottleneck pipe.
__device__ __forceinline__ unsigned int pk2t(float a, float b) {
  return (__float_as_uint(a) >> 16) | (__float_as_uint(b) & 0xFFFF0000u);
}

// async global->LDS 16B: dst must be wave-uniform (HW adds lane*16)
__device__ __forceinline__ void gll16(const void* g, void* lds) {
  __builtin_amdgcn_global_load_lds(
      (const __attribute__((address_space(1))) unsigned int*)g,
      (__attribute__((address_space(3))) unsigned int*)lds, 16, 0, 0);
}

// ---------------- merged prep: x->bf16 + 4 weight transposes, one launch ----------------
__global__ __launch_bounds__(256)
void prep(const float* __restrict__ x, unsigned short* __restrict__ xb,
          const float* __restrict__ Wq, const float* __restrict__ Wo,
          const float* __restrict__ Wk, const float* __restrict__ Wv,
          unsigned short* __restrict__ wqkvt, unsigned short* __restrict__ wot) {
  __shared__ float tile[32][33];
  const int bid = blockIdx.x;
  const int t = threadIdx.x;

  if (bid < 4096) {
    int i = bid * 256 + t;
    const int stride = 4096 * 256;
    #pragma unroll
    for (int rep = 0; rep < 2; ++rep, i += stride) {
      float4 v = reinterpret_cast<const float4*>(x)[i];
      ushort4 o;
      o.x = f2bf(v.x); o.y = f2bf(v.y); o.z = f2bf(v.z); o.w = f2bf(v.w);
      reinterpret_cast<ushort4*>(xb)[i] = o;
    }
    return;
  }

  const float* W;
  unsigned short* Wt;
  int K = 2048, N, bx, by;
  if (bid < 12288) {
    int r = bid - 4096;
    int z = r >> 12, rr = r & 4095;
    bx = rr & 63; by = rr >> 6; N = 2048;
    W = z ? Wo : Wq;
    Wt = z ? wot : wqkvt;
  } else {
    int r = bid - 12288;
    int z = r >> 8, rr = r & 255;
    bx = rr & 3; by = rr >> 2; N = 128;
    W = z ? Wv : Wk;
    Wt = wqkvt + (size_t)(z ? 2176 : 2048) * 2048;
  }
  const int tx = t & 31, ty = t >> 5;
  const int n0 = bx * 32, k0 = by * 32;
  #pragma unroll
  for (int i = 0; i < 32; i += 8)
    tile[ty + i][tx] = W[(size_t)(k0 + ty + i) * N + n0 + tx];
  __syncthreads();
  #pragma unroll
  for (int i = 0; i < 32; i += 8)
    Wt[(size_t)(n0 + ty + i) * K + k0 + tx] = f2bf(tile[tx][ty + i]);
}

// ---------------- GEMM: C = A[M][K] @ Bt[N][K]^T + bias ----------------
// 128x64 tile, BK=64, 256 threads = 4 waves (2M x 2N of 64x32 each).
// LDS 24KB; grids >=1024 blocks (~4/CU) for TLP (R13).
// XCD swizzle (T1): flat bid remapped so each XCD gets a contiguous grid chunk
// (consecutive blocks share the 512KB A-panel in that XCD's L2). nwg%8==0 required.
// MODE 1: f32 out C[M][N] (+b0)
// MODE 3: fused QKV epilogue (N=2304): col<2048 -> qb bf16 (acc+b0)*cmul;
//         col<2176 -> kbuf bf16 (+b1); else -> vt transposed bf16 (+b2)
template <int MODE>
__global__ __launch_bounds__(256)
void gemm_nt(const unsigned short* __restrict__ A, const unsigned short* __restrict__ Bt,
             const float* __restrict__ b0, const float* __restrict__ b1,
             const float* __restrict__ b2,
             void* __restrict__ C, unsigned short* __restrict__ C2,
             unsigned short* __restrict__ C3, int M, int N, int K, float cmul) {
  __shared__ unsigned short lA[128 * 64];   // 16KB
  __shared__ unsigned short lB[64 * 64];    // 8KB
  const int t = threadIdx.x;
  const int lane = t & 63;
  const int w = t >> 6;
  const int wr = w >> 1, wc = w & 1;
  const int r15 = lane & 15, g4 = lane >> 4;

  // T1 XCD-aware swizzle (bijective since nwg % 8 == 0)
  const int nwg = gridDim.x * gridDim.y;
  int bid = blockIdx.y * gridDim.x + blockIdx.x;
  bid = (bid & 7) * (nwg >> 3) + (bid >> 3);
  const int tileM = (bid / gridDim.x) * 128;
  const int tileN = (bid % gridDim.x) * 64;

  f32x4 acc[4][2];
  #pragma unroll
  for (int i = 0; i < 4; i++)
    #pragma unroll
    for (int j = 0; j < 2; j++) acc[i][j] = (f32x4){0.f, 0.f, 0.f, 0.f};

  const int nkt = K >> 6;
  for (int kt = 0; kt < nkt; ++kt) {
    const int k0 = kt * 64;
    #pragma unroll
    for (int i = 0; i < 4; ++i) {
      int flat = i * 256 + t;
      int row = flat >> 3, gc = flat & 7;
      unsigned lb = (unsigned)(i * 256 + w * 64) * 16;
      gll16(A + (size_t)(tileM + row) * K + k0 + gc * 8, (char*)lA + lb);
    }
    #pragma unroll
    for (int i = 0; i < 2; ++i) {
      int flat = i * 256 + t;
      int row = flat >> 3, gc = flat & 7;
      unsigned lb = (unsigned)(i * 256 + w * 64) * 16;
      gll16(Bt + (size_t)(tileN + row) * K + k0 + gc * 8, (char*)lB + lb);
    }
    asm volatile("s_waitcnt vmcnt(0)" ::: "memory");
    __builtin_amdgcn_s_barrier();
    asm volatile("" ::: "memory");

    #pragma unroll
    for (int kk = 0; kk < 2; ++kk) {
      short8 af[4], bf[2];
      #pragma unroll
      for (int mt = 0; mt < 4; ++mt)
        af[mt] = *reinterpret_cast<const short8*>(&lA[(wr * 64 + mt * 16 + r15) * 64 + kk * 32 + g4 * 8]);
      #pragma unroll
      for (int nt = 0; nt < 2; ++nt)
        bf[nt] = *reinterpret_cast<const short8*>(&lB[(wc * 32 + nt * 16 + r15) * 64 + kk * 32 + g4 * 8]);
      #pragma unroll
      for (int mt = 0; mt < 4; ++mt)
        #pragma unroll
        for (int nt = 0; nt < 2; ++nt)
          acc[mt][nt] = __builtin_amdgcn_mfma_f32_16x16x32_bf16(af[mt], bf[nt], acc[mt][nt], 0, 0, 0);
    }
    asm volatile("" ::: "memory");
    __builtin_amdgcn_s_barrier();
  }

  // epilogue: C/D layout col=lane&15, row=(lane>>4)*4+reg
  #pragma unroll
  for (int mt = 0; mt < 4; ++mt) {
    #pragma unroll
    for (int nt = 0; nt < 2; ++nt) {
      int col = tileN + wc * 32 + nt * 16 + r15;
      #pragma unroll
      for (int r = 0; r < 4; ++r) {
        int row = tileM + wr * 64 + mt * 16 + g4 * 4 + r;
        float v = acc[mt][nt][r];
        if (MODE == 1) {
          ((float*)C)[(size_t)row * N + col] = v + b0[col];
        } else {
          if (col < 2048) {
            ((unsigned short*)C)[(size_t)row * 2048 + col] = f2bf((v + b0[col]) * cmul);
          } else if (col < 2176) {
            int dd = col - 2048;
            C2[(size_t)row * 128 + dd] = f2bf(v + b1[dd]);
          } else {
            int dd = col - 2176;
            int bb = row >> 11, s = row & 2047;
            C3[((size_t)bb * 128 + dd) * 2048 + s] = f2bf(v + b2[dd]);  // v^T [b][d][s]
          }
        }
      }
    }
  }
}

// ---------------- flash attention (MQA): 8 waves, QBLK=128, 1 head/block ----------------
// grid (S/128, H, B), 512 threads = 8 waves; wave owns 16 q rows (q = r15 per lane).
// qb [B*S][2048] bf16 (pre-scaled by log2(e)/sqrt(d)), kb [B*S][128] bf16,
// vt [B][128][S] bf16, ob [B*S][2048] bf16
// QK^T = mfma(K,Q): D[kv][q]; softmax lane-local (q=r15); P=exp2(s'-m').
// PV  = mfma(V^T,P^T): D[d][q]; rescale lane-local.
// 16 waves/CU (2 blocks x 8); P/O packed with truncating bf16 (VALU is the pipe).
__global__ __launch_bounds__(512, 4)
void flash_mqa(const unsigned short* __restrict__ qb, const unsigned short* __restrict__ kb,
               const unsigned short* __restrict__ vt, unsigned short* __restrict__ ob) {
  __shared__ unsigned short lK[2][64 * 128];   // [kv][d], swizzled
  __shared__ unsigned short lV[2][128 * 64];   // [d][kv], swizzled
  __shared__ unsigned short lP[8][16 * 64];    // per-wave [q][kv], granule-swizzled

  const int t = threadIdx.x;
  const int lane = t & 63;
  const int w = t >> 6;                 // 8 waves
  const int r15 = lane & 15, g4 = lane >> 4;
  const int qt = blockIdx.x, h = blockIdx.y, b = blockIdx.z;
  const int q0 = qt * 128 + w * 16;

  // persistent Q B-frags: row q=r15, k = g4*8
  short8 qf[4];
  const size_t qrow = (size_t)(b * 2048 + q0 + r15);
  #pragma unroll
  for (int kk = 0; kk < 4; ++kk)
    qf[kk] = *reinterpret_cast<const short8*>(&qb[qrow * 2048 + h * 128 + kk * 32 + g4 * 8]);

  f32x4 oacc[8];   // O^T: oacc[ot][r] -> d = ot*16+g4*4+r, q = r15
  #pragma unroll
  for (int i = 0; i < 8; i++) oacc[i] = (f32x4){0.f, 0.f, 0.f, 0.f};
  float m_q = -1e30f, l_q = 0.f;   // log2 units

  const unsigned short* kbase = kb + (size_t)b * 2048 * 128;
  const unsigned short* vbase = vt + (size_t)b * 128 * 2048;

  // 512 threads: K tile 1024 granules (2/thread), V tile 1024 granules (2/thread)
  auto stage = [&](int buf, int kv0) {
    #pragma unroll
    for (int i = 0; i < 2; ++i) {
      int flat = i * 512 + t;
      unsigned lb = (unsigned)(i * 512 + w * 64) * 16;
      { int row = flat >> 4, gc = flat & 15;
        gll16(kbase + (size_t)(kv0 + row) * 128 + ((gc ^ (row & 15)) << 3), (char*)lK[buf] + lb); }
      { int row = flat >> 3, gc = flat & 7;
        gll16(vbase + (size_t)row * 2048 + kv0 + ((gc ^ (row & 7)) << 3), (char*)lV[buf] + lb); }
    }
  };

  stage(0, 0);
  int cur = 0;
  for (int it = 0; it < 32; ++it) {
    if (it < 31) {
      stage(cur ^ 1, (it + 1) * 64);
      asm volatile("s_waitcnt vmcnt(4)" ::: "memory");  // current tile's 4 loads done
    } else {
      asm volatile("s_waitcnt vmcnt(0)" ::: "memory");
    }
    __builtin_amdgcn_s_barrier();
    asm volatile("" ::: "memory");

    const unsigned short* cK = lK[cur];
    const unsigned short* cV = lV[cur];

    // ---- QK^T swapped: s[ct] = K_sub(ct) x Q -> D[kv][q] (log2-scaled) ----
    f32x4 s[4];
    #pragma unroll
    for (int ct = 0; ct < 4; ct++) s[ct] = (f32x4){0.f, 0.f, 0.f, 0.f};
    #pragma unroll
    for (int kk = 0; kk < 4; ++kk) {
      #pragma unroll
      for (int ct = 0; ct < 4; ++ct) {
        const int krow = ct * 16 + r15;
        const int kg = (kk * 4 + g4) ^ (krow & 15);
        short8 kf = *reinterpret_cast<const short8*>(&cK[krow * 128 + kg * 8]);
        s[ct] = __builtin_amdgcn_mfma_f32_16x16x32_bf16(kf, qf[kk], s[ct], 0, 0, 0);
      }
    }

    // ---- softmax: lane owns q=r15 with 16 kv values ----
    float mx = s[0][0];
    #pragma unroll
    for (int ct = 0; ct < 4; ++ct)
      #pragma unroll
      for (int r = 0; r < 4; ++r) mx = fmaxf(mx, s[ct][r]);
    mx = fmaxf(mx, __shfl_xor(mx, 16));
    mx = fmaxf(mx, __shfl_xor(mx, 32));
    // T13 defer-max: rescale only when growth > 8/ln2 (P bounded by e^8)
    if (__any(mx > m_q + 11.5416f)) {
      float mn = fmaxf(m_q, mx);
      float rf = exp2f(m_q - mn);   // lane-local (q=r15)
      m_q = mn;
      l_q *= rf;
      #pragma unroll
      for (int ot = 0; ot < 8; ++ot)
        #pragma unroll
        for (int r = 0; r < 4; ++r) oacc[ot][r] *= rf;
    }
    // ---- P = exp2(s-m), truncating pack, b64 write to lP (granule ^ r15) ----
    #pragma unroll
    for (int ct = 0; ct < 4; ++ct) {
      float p0 = exp2f(s[ct][0] - m_q);
      float p1 = exp2f(s[ct][1] - m_q);
      float p2 = exp2f(s[ct][2] - m_q);
      float p3 = exp2f(s[ct][3] - m_q);
      l_q += (p0 + p1) + (p2 + p3);
      const int gi = (ct * 4 + g4) ^ r15;
      *reinterpret_cast<uint2*>(&lP[w][r15 * 64 + gi * 4]) = make_uint2(pk2t(p0, p1), pk2t(p2, p3));
    }

    // ---- PV swapped: oacc = V^T_sub(ot) x P^T -> D[d][q] ----
    #pragma unroll
    for (int kk = 0; kk < 2; ++kk) {
      const int gA = (kk * 8 + g4 * 2) ^ r15;
      const int gB = (kk * 8 + g4 * 2 + 1) ^ r15;
      const uint2 wa = *reinterpret_cast<const uint2*>(&lP[w][r15 * 64 + gA * 4]);
      const uint2 wb = *reinterpret_cast<const uint2*>(&lP[w][r15 * 64 + gB * 4]);
      uint4v pw = {wa.x, wa.y, wb.x, wb.y};
      short8 pf = __builtin_bit_cast(short8, pw);
      #pragma unroll
      for (int ot = 0; ot < 8; ++ot) {
        const int vrow = ot * 16 + r15;
        const int vg = (kk * 4 + g4) ^ (vrow & 7);
        short8 vf = *reinterpret_cast<const short8*>(&cV[vrow * 64 + vg * 8]);
        oacc[ot] = __builtin_amdgcn_mfma_f32_16x16x32_bf16(vf, pf, oacc[ot], 0, 0, 0);
      }
    }

    asm volatile("" ::: "memory");
    __builtin_amdgcn_s_barrier();   // all waves done reading buf[cur] before restage
    cur ^= 1;
  }

  // epilogue: cross-lane l reduce (kv partials live on lanes r15, r15+16, +32, +48)
  float l = l_q;
  l += __shfl_xor(l, 16);
  l += __shfl_xor(l, 32);
  const float inv = 1.0f / l;
  const int row = q0 + r15;
  const size_t base = ((size_t)(b * 2048 + row)) * 2048 + h * 128;
  #pragma unroll
  for (int ot = 0; ot < 8; ++ot) {
    uint2 pw = make_uint2(pk2t(oacc[ot][0] * inv, oacc[ot][1] * inv),
                          pk2t(oacc[ot][2] * inv, oacc[ot][3] * inv));
    *reinterpret_cast<uint2*>(&ob[base + ot * 16 + g4 * 4]) = pw;
  }
}

extern "C" void kernel_launch(void* const* d_in, const int* in_sizes, int n_in,
                              void* d_out, int out_size, void* d_ws, size_t ws_size,
                              hipStream_t stream) {
  const float* x  = (const float*)d_in[0];
  const float* Wq = (const float*)d_in[1];
  const float* bq = (const float*)d_in[2];
  const float* Wk = (const float*)d_in[3];
  const float* bk = (const float*)d_in[4];
  const float* Wv = (const float*)d_in[5];
  const float* bv = (const float*)d_in[6];
  const float* Wo = (const float*)d_in[7];
  const float* bo = (const float*)d_in[8];
  float* out = (float*)d_out;

  char* ws = (char*)d_ws;
  size_t off = 0;
  auto alloc = [&](size_t elems) {
    unsigned short* p = (unsigned short*)(ws + off);
    off += (elems * 2 + 255) & ~(size_t)255;
    return p;
  };
  unsigned short* xb    = alloc(8388608);   // x bf16 [4096][2048]
  unsigned short* qb    = alloc(8388608);   // q bf16 [4096][2048] (pre-scaled, log2 units)
  unsigned short* ob    = alloc(8388608);   // attn out bf16 [4096][2048]
  unsigned short* wqkvt = alloc(4718592);   // [Wq^T;Wk^T;Wv^T] [2304][2048]
  unsigned short* wot   = alloc(4194304);   // Wo^T [2048][2048]
  unsigned short* kbuf  = alloc(524288);    // k bf16 [4096][128]
  unsigned short* vtb   = alloc(524288);    // v^T bf16 [2][128][2048]

  // 1/sqrt(128) * log2(e): scores come out of QK^T already in log2 units
  const float qscale = 0.08838834764831845f * 1.44269504088896f;

  prep<<<12800, 256, 0, stream>>>(x, xb, Wq, Wo, Wk, Wv, wqkvt, wot);

  gemm_nt<3><<<dim3(36, 32), 256, 0, stream>>>(xb, wqkvt, bq, bk, bv,
                                               qb, kbuf, vtb, 4096, 2304, 2048, qscale);
  flash_mqa<<<dim3(16, 16, 2), 512, 0, stream>>>(qb, kbuf, vtb, ob);
  gemm_nt<1><<<dim3(32, 32), 256, 0, stream>>>(ob, wot, bo, nullptr, nullptr,
                                               out, nullptr, nullptr, 4096, 2048, 2048, 1.0f);
}

// Round 16
// 239.850 us; speedup vs baseline: 1.2115x; 1.0088x over previous
//
#include <hip/hip_runtime.h>

// MQA forward on MI355X (gfx950), bf16 MFMA path.
// B=2, S=2048, D_MODEL=2048, H=16, HEAD_DIM=128 (MQA: K/V shared across heads).
// R2: T2 XOR-swizzle in flash (bank conflicts 9.1e7 -> 0; 290 -> 191 us).
// R6: softmax-lite (deferred l-sum, T13 defer-max): 187 -> 167 us.
// R7: swapped-operand flash (lane owns one q-row): 167 -> 139 us.
// R8: cvt_pk asm REVERTED (m240); exp2-direct kept.
// R12/R13: GEMM grid-starvation fixed (128x64 tiles, ~4.5 blocks/CU): 284.8 -> 258.4.
// R14: flash 8 waves x 512 thr, QBLK=128: 16 waves/CU: 258.4 -> 246.1.
// R15: flash truncating bf16 P/O pack: flash 114.7 -> 105.9; GEMM T1 XCD swizzle
//      REGRESSED ~4.6us (L3-fit working set, m160 caveat confirmed).
// R16: T1 swizzle REVERTED; flash row-max via v_max3_f32 chains (T17).

typedef __attribute__((ext_vector_type(8))) short short8;
typedef __attribute__((ext_vector_type(4))) float f32x4;
typedef __attribute__((ext_vector_type(4))) unsigned int uint4v;

__device__ __forceinline__ unsigned short f2bf(float f) {
  unsigned int u = __float_as_uint(f);
  u += 0x7FFF + ((u >> 16) & 1);   // RNE
  return (unsigned short)(u >> 16);
}

__device__ __forceinline__ unsigned int pk2(float a, float b) {
  return (unsigned int)f2bf(a) | ((unsigned int)f2bf(b) << 16);
}

// truncating pack: 3 VALU ops; rel err <= 2^-8 -- flash P/O hot path only.
__device__ __forceinline__ unsigned int pk2t(float a, float b) {
  return (__float_as_uint(a) >> 16) | (__float_as_uint(b) & 0xFFFF0000u);
}

// async global->LDS 16B: dst must be wave-uniform (HW adds lane*16)
__device__ __forceinline__ void gll16(const void* g, void* lds) {
  __builtin_amdgcn_global_load_lds(
      (const __attribute__((address_space(1))) unsigned int*)g,
      (__attribute__((address_space(3))) unsigned int*)lds, 16, 0, 0);
}

// ---------------- merged prep: x->bf16 + 4 weight transposes, one launch ----------------
__global__ __launch_bounds__(256)
void prep(const float* __restrict__ x, unsigned short* __restrict__ xb,
          const float* __restrict__ Wq, const float* __restrict__ Wo,
          const float* __restrict__ Wk, const float* __restrict__ Wv,
          unsigned short* __restrict__ wqkvt, unsigned short* __restrict__ wot) {
  __shared__ float tile[32][33];
  const int bid = blockIdx.x;
  const int t = threadIdx.x;

  if (bid < 4096) {
    int i = bid * 256 + t;
    const int stride = 4096 * 256;
    #pragma unroll
    for (int rep = 0; rep < 2; ++rep, i += stride) {
      float4 v = reinterpret_cast<const float4*>(x)[i];
      ushort4 o;
      o.x = f2bf(v.x); o.y = f2bf(v.y); o.z = f2bf(v.z); o.w = f2bf(v.w);
      reinterpret_cast<ushort4*>(xb)[i] = o;
    }
    return;
  }

  const float* W;
  unsigned short* Wt;
  int K = 2048, N, bx, by;
  if (bid < 12288) {
    int r = bid - 4096;
    int z = r >> 12, rr = r & 4095;
    bx = rr & 63; by = rr >> 6; N = 2048;
    W = z ? Wo : Wq;
    Wt = z ? wot : wqkvt;
  } else {
    int r = bid - 12288;
    int z = r >> 8, rr = r & 255;
    bx = rr & 3; by = rr >> 2; N = 128;
    W = z ? Wv : Wk;
    Wt = wqkvt + (size_t)(z ? 2176 : 2048) * 2048;
  }
  const int tx = t & 31, ty = t >> 5;
  const int n0 = bx * 32, k0 = by * 32;
  #pragma unroll
  for (int i = 0; i < 32; i += 8)
    tile[ty + i][tx] = W[(size_t)(k0 + ty + i) * N + n0 + tx];
  __syncthreads();
  #pragma unroll
  for (int i = 0; i < 32; i += 8)
    Wt[(size_t)(n0 + ty + i) * K + k0 + tx] = f2bf(tile[tx][ty + i]);
}

// ---------------- GEMM: C = A[M][K] @ Bt[N][K]^T + bias ----------------
// 128x64 tile, BK=64, 256 threads = 4 waves (2M x 2N of 64x32 each).
// LDS 24KB; grids >=1024 blocks (~4/CU) for TLP (R13). No XCD swizzle (R16).
// MODE 1: f32 out C[M][N] (+b0)
// MODE 3: fused QKV epilogue (N=2304): col<2048 -> qb bf16 (acc+b0)*cmul;
//         col<2176 -> kbuf bf16 (+b1); else -> vt transposed bf16 (+b2)
template <int MODE>
__global__ __launch_bounds__(256)
void gemm_nt(const unsigned short* __restrict__ A, const unsigned short* __restrict__ Bt,
             const float* __restrict__ b0, const float* __restrict__ b1,
             const float* __restrict__ b2,
             void* __restrict__ C, unsigned short* __restrict__ C2,
             unsigned short* __restrict__ C3, int M, int N, int K, float cmul) {
  __shared__ unsigned short lA[128 * 64];   // 16KB
  __shared__ unsigned short lB[64 * 64];    // 8KB
  const int t = threadIdx.x;
  const int lane = t & 63;
  const int w = t >> 6;
  const int wr = w >> 1, wc = w & 1;
  const int r15 = lane & 15, g4 = lane >> 4;
  const int tileM = blockIdx.y * 128;
  const int tileN = blockIdx.x * 64;

  f32x4 acc[4][2];
  #pragma unroll
  for (int i = 0; i < 4; i++)
    #pragma unroll
    for (int j = 0; j < 2; j++) acc[i][j] = (f32x4){0.f, 0.f, 0.f, 0.f};

  const int nkt = K >> 6;
  for (int kt = 0; kt < nkt; ++kt) {
    const int k0 = kt * 64;
    #pragma unroll
    for (int i = 0; i < 4; ++i) {
      int flat = i * 256 + t;
      int row = flat >> 3, gc = flat & 7;
      unsigned lb = (unsigned)(i * 256 + w * 64) * 16;
      gll16(A + (size_t)(tileM + row) * K + k0 + gc * 8, (char*)lA + lb);
    }
    #pragma unroll
    for (int i = 0; i < 2; ++i) {
      int flat = i * 256 + t;
      int row = flat >> 3, gc = flat & 7;
      unsigned lb = (unsigned)(i * 256 + w * 64) * 16;
      gll16(Bt + (size_t)(tileN + row) * K + k0 + gc * 8, (char*)lB + lb);
    }
    asm volatile("s_waitcnt vmcnt(0)" ::: "memory");
    __builtin_amdgcn_s_barrier();
    asm volatile("" ::: "memory");

    #pragma unroll
    for (int kk = 0; kk < 2; ++kk) {
      short8 af[4], bf[2];
      #pragma unroll
      for (int mt = 0; mt < 4; ++mt)
        af[mt] = *reinterpret_cast<const short8*>(&lA[(wr * 64 + mt * 16 + r15) * 64 + kk * 32 + g4 * 8]);
      #pragma unroll
      for (int nt = 0; nt < 2; ++nt)
        bf[nt] = *reinterpret_cast<const short8*>(&lB[(wc * 32 + nt * 16 + r15) * 64 + kk * 32 + g4 * 8]);
      #pragma unroll
      for (int mt = 0; mt < 4; ++mt)
        #pragma unroll
        for (int nt = 0; nt < 2; ++nt)
          acc[mt][nt] = __builtin_amdgcn_mfma_f32_16x16x32_bf16(af[mt], bf[nt], acc[mt][nt], 0, 0, 0);
    }
    asm volatile("" ::: "memory");
    __builtin_amdgcn_s_barrier();
  }

  // epilogue: C/D layout col=lane&15, row=(lane>>4)*4+reg
  #pragma unroll
  for (int mt = 0; mt < 4; ++mt) {
    #pragma unroll
    for (int nt = 0; nt < 2; ++nt) {
      int col = tileN + wc * 32 + nt * 16 + r15;
      #pragma unroll
      for (int r = 0; r < 4; ++r) {
        int row = tileM + wr * 64 + mt * 16 + g4 * 4 + r;
        float v = acc[mt][nt][r];
        if (MODE == 1) {
          ((float*)C)[(size_t)row * N + col] = v + b0[col];
        } else {
          if (col < 2048) {
            ((unsigned short*)C)[(size_t)row * 2048 + col] = f2bf((v + b0[col]) * cmul);
          } else if (col < 2176) {
            int dd = col - 2048;
            C2[(size_t)row * 128 + dd] = f2bf(v + b1[dd]);
          } else {
            int dd = col - 2176;
            int bb = row >> 11, s = row & 2047;
            C3[((size_t)bb * 128 + dd) * 2048 + s] = f2bf(v + b2[dd]);  // v^T [b][d][s]
          }
        }
      }
    }
  }
}

// ---------------- flash attention (MQA): 8 waves, QBLK=128, 1 head/block ----------------
// grid (S/128, H, B), 512 threads = 8 waves; wave owns 16 q rows (q = r15 per lane).
// qb [B*S][2048] bf16 (pre-scaled by log2(e)/sqrt(d)), kb [B*S][128] bf16,
// vt [B][128][S] bf16, ob [B*S][2048] bf16
// QK^T = mfma(K,Q): D[kv][q]; softmax lane-local (q=r15); P=exp2(s'-m').
// PV  = mfma(V^T,P^T): D[d][q]; rescale lane-local.
// 16 waves/CU; truncating P/O pack; row-max via v_max3_f32 chains (T17).
__global__ __launch_bounds__(512, 4)
void flash_mqa(const unsigned short* __restrict__ qb, const unsigned short* __restrict__ kb,
               const unsigned short* __restrict__ vt, unsigned short* __restrict__ ob) {
  __shared__ unsigned short lK[2][64 * 128];   // [kv][d], swizzled
  __shared__ unsigned short lV[2][128 * 64];   // [d][kv], swizzled
  __shared__ unsigned short lP[8][16 * 64];    // per-wave [q][kv], granule-swizzled

  const int t = threadIdx.x;
  const int lane = t & 63;
  const int w = t >> 6;                 // 8 waves
  const int r15 = lane & 15, g4 = lane >> 4;
  const int qt = blockIdx.x, h = blockIdx.y, b = blockIdx.z;
  const int q0 = qt * 128 + w * 16;

  // persistent Q B-frags: row q=r15, k = g4*8
  short8 qf[4];
  const size_t qrow = (size_t)(b * 2048 + q0 + r15);
  #pragma unroll
  for (int kk = 0; kk < 4; ++kk)
    qf[kk] = *reinterpret_cast<const short8*>(&qb[qrow * 2048 + h * 128 + kk * 32 + g4 * 8]);

  f32x4 oacc[8];   // O^T: oacc[ot][r] -> d = ot*16+g4*4+r, q = r15
  #pragma unroll
  for (int i = 0; i < 8; i++) oacc[i] = (f32x4){0.f, 0.f, 0.f, 0.f};
  float m_q = -1e30f, l_q = 0.f;   // log2 units

  const unsigned short* kbase = kb + (size_t)b * 2048 * 128;
  const unsigned short* vbase = vt + (size_t)b * 128 * 2048;

  // 512 threads: K tile 1024 granules (2/thread), V tile 1024 granules (2/thread)
  auto stage = [&](int buf, int kv0) {
    #pragma unroll
    for (int i = 0; i < 2; ++i) {
      int flat = i * 512 + t;
      unsigned lb = (unsigned)(i * 512 + w * 64) * 16;
      { int row = flat >> 4, gc = flat & 15;
        gll16(kbase + (size_t)(kv0 + row) * 128 + ((gc ^ (row & 15)) << 3), (char*)lK[buf] + lb); }
      { int row = flat >> 3, gc = flat & 7;
        gll16(vbase + (size_t)row * 2048 + kv0 + ((gc ^ (row & 7)) << 3), (char*)lV[buf] + lb); }
    }
  };

  stage(0, 0);
  int cur = 0;
  for (int it = 0; it < 32; ++it) {
    if (it < 31) {
      stage(cur ^ 1, (it + 1) * 64);
      asm volatile("s_waitcnt vmcnt(4)" ::: "memory");  // current tile's 4 loads done
    } else {
      asm volatile("s_waitcnt vmcnt(0)" ::: "memory");
    }
    __builtin_amdgcn_s_barrier();
    asm volatile("" ::: "memory");

    const unsigned short* cK = lK[cur];
    const unsigned short* cV = lV[cur];

    // ---- QK^T swapped: s[ct] = K_sub(ct) x Q -> D[kv][q] (log2-scaled) ----
    f32x4 s[4];
    #pragma unroll
    for (int ct = 0; ct < 4; ct++) s[ct] = (f32x4){0.f, 0.f, 0.f, 0.f};
    #pragma unroll
    for (int kk = 0; kk < 4; ++kk) {
      #pragma unroll
      for (int ct = 0; ct < 4; ++ct) {
        const int krow = ct * 16 + r15;
        const int kg = (kk * 4 + g4) ^ (krow & 15);
        short8 kf = *reinterpret_cast<const short8*>(&cK[krow * 128 + kg * 8]);
        s[ct] = __builtin_amdgcn_mfma_f32_16x16x32_bf16(kf, qf[kk], s[ct], 0, 0, 0);
      }
    }

    // ---- softmax: lane owns q=r15 with 16 kv values; max via v_max3 chains ----
    float mx = fmaxf(fmaxf(s[0][0], s[0][1]), s[0][2]);
    mx = fmaxf(fmaxf(mx, s[0][3]), s[1][0]);
    mx = fmaxf(fmaxf(mx, s[1][1]), s[1][2]);
    mx = fmaxf(fmaxf(mx, s[1][3]), s[2][0]);
    mx = fmaxf(fmaxf(mx, s[2][1]), s[2][2]);
    mx = fmaxf(fmaxf(mx, s[2][3]), s[3][0]);
    mx = fmaxf(fmaxf(mx, s[3][1]), s[3][2]);
    mx = fmaxf(mx, s[3][3]);
    mx = fmaxf(mx, __shfl_xor(mx, 16));
    mx = fmaxf(mx, __shfl_xor(mx, 32));
    // T13 defer-max: rescale only when growth > 8/ln2 (P bounded by e^8)
    if (__any(mx > m_q + 11.5416f)) {
      float mn = fmaxf(m_q, mx);
      float rf = exp2f(m_q - mn);   // lane-local (q=r15)
      m_q = mn;
      l_q *= rf;
      #pragma unroll
      for (int ot = 0; ot < 8; ++ot)
        #pragma unroll
        for (int r = 0; r < 4; ++r) oacc[ot][r] *= rf;
    }
    // ---- P = exp2(s-m), truncating pack, b64 write to lP (granule ^ r15) ----
    #pragma unroll
    for (int ct = 0; ct < 4; ++ct) {
      float p0 = exp2f(s[ct][0] - m_q);
      float p1 = exp2f(s[ct][1] - m_q);
      float p2 = exp2f(s[ct][2] - m_q);
      float p3 = exp2f(s[ct][3] - m_q);
      l_q += (p0 + p1) + (p2 + p3);
      const int gi = (ct * 4 + g4) ^ r15;
      *reinterpret_cast<uint2*>(&lP[w][r15 * 64 + gi * 4]) = make_uint2(pk2t(p0, p1), pk2t(p2, p3));
    }

    // ---- PV swapped: oacc = V^T_sub(ot) x P^T -> D[d][q] ----
    #pragma unroll
    for (int kk = 0; kk < 2; ++kk) {
      const int gA = (kk * 8 + g4 * 2) ^ r15;
      const int gB = (kk * 8 + g4 * 2 + 1) ^ r15;
      const uint2 wa = *reinterpret_cast<const uint2*>(&lP[w][r15 * 64 + gA * 4]);
      const uint2 wb = *reinterpret_cast<const uint2*>(&lP[w][r15 * 64 + gB * 4]);
      uint4v pw = {wa.x, wa.y, wb.x, wb.y};
      short8 pf = __builtin_bit_cast(short8, pw);
      #pragma unroll
      for (int ot = 0; ot < 8; ++ot) {
        const int vrow = ot * 16 + r15;
        const int vg = (kk * 4 + g4) ^ (vrow & 7);
        short8 vf = *reinterpret_cast<const short8*>(&cV[vrow * 64 + vg * 8]);
        oacc[ot] = __builtin_amdgcn_mfma_f32_16x16x32_bf16(vf, pf, oacc[ot], 0, 0, 0);
      }
    }

    asm volatile("" ::: "memory");
    __builtin_amdgcn_s_barrier();   // all waves done reading buf[cur] before restage
    cur ^= 1;
  }

  // epilogue: cross-lane l reduce (kv partials live on lanes r15, r15+16, +32, +48)
  float l = l_q;
  l += __shfl_xor(l, 16);
  l += __shfl_xor(l, 32);
  const float inv = 1.0f / l;
  const int row = q0 + r15;
  const size_t base = ((size_t)(b * 2048 + row)) * 2048 + h * 128;
  #pragma unroll
  for (int ot = 0; ot < 8; ++ot) {
    uint2 pw = make_uint2(pk2t(oacc[ot][0] * inv, oacc[ot][1] * inv),
                          pk2t(oacc[ot][2] * inv, oacc[ot][3] * inv));
    *reinterpret_cast<uint2*>(&ob[base + ot * 16 + g4 * 4]) = pw;
  }
}

extern "C" void kernel_launch(void* const* d_in, const int* in_sizes, int n_in,
                              void* d_out, int out_size, void* d_ws, size_t ws_size,
                              hipStream_t stream) {
  const float* x  = (const float*)d_in[0];
  const float* Wq = (const float*)d_in[1];
  const float* bq = (const float*)d_in[2];
  const float* Wk = (const float*)d_in[3];
  const float* bk = (const float*)d_in[4];
  const float* Wv = (const float*)d_in[5];
  const float* bv = (const float*)d_in[6];
  const float* Wo = (const float*)d_in[7];
  const float* bo = (const float*)d_in[8];
  float* out = (float*)d_out;

  char* ws = (char*)d_ws;
  size_t off = 0;
  auto alloc = [&](size_t elems) {
    unsigned short* p = (unsigned short*)(ws + off);
    off += (elems * 2 + 255) & ~(size_t)255;
    return p;
  };
  unsigned short* xb    = alloc(8388608);   // x bf16 [4096][2048]
  unsigned short* qb    = alloc(8388608);   // q bf16 [4096][2048] (pre-scaled, log2 units)
  unsigned short* ob    = alloc(8388608);   // attn out bf16 [4096][2048]
  unsigned short* wqkvt = alloc(4718592);   // [Wq^T;Wk^T;Wv^T] [2304][2048]
  unsigned short* wot   = alloc(4194304);   // Wo^T [2048][2048]
  unsigned short* kbuf  = alloc(524288);    // k bf16 [4096][128]
  unsigned short* vtb   = alloc(524288);    // v^T bf16 [2][128][2048]

  // 1/sqrt(128) * log2(e): scores come out of QK^T already in log2 units
  const float qscale = 0.08838834764831845f * 1.44269504088896f;

  prep<<<12800, 256, 0, stream>>>(x, xb, Wq, Wo, Wk, Wv, wqkvt, wot);

  gemm_nt<3><<<dim3(36, 32), 256, 0, stream>>>(xb, wqkvt, bq, bk, bv,
                                               qb, kbuf, vtb, 4096, 2304, 2048, qscale);
  flash_mqa<<<dim3(16, 16, 2), 512, 0, stream>>>(qb, kbuf, vtb, ob);
  gemm_nt<1><<<dim3(32, 32), 256, 0, stream>>>(ob, wot, bo, nullptr, nullptr,
                                               out, nullptr, nullptr, 4096, 2048, 2048, 1.0f);
}